// Round 1
// baseline (7906.512 us; speedup 1.0000x reference)
//
#include <hip/hip_runtime.h>
#include <math.h>

#define NN 100000
#define NE 2000000
#define FIN 32
#define H 32
#define NC 40

__device__ __forceinline__ float sigm_(float x) {
    return 1.0f / (1.0f + __expf(-x));
}
__device__ __forceinline__ float tanh_(float x) {
    x = fminf(fmaxf(x, -20.0f), 20.0f);
    float e = __expf(2.0f * x);
    return (e - 1.0f) / (e + 1.0f);
}

// ---------------- K1: h1 = x @ W1p ; m1 = h1 @ W1m ----------------
__global__ __launch_bounds__(256) void k1_proj(const float* __restrict__ x,
                                               const float* __restrict__ Wp,
                                               const float* __restrict__ Wm,
                                               float* __restrict__ h1,
                                               float* __restrict__ m1) {
    __shared__ float sWp[FIN * H];
    __shared__ float sWm[H * H];
    __shared__ float sx[8][FIN];
    __shared__ float sh[8][H];
    int tid = threadIdx.x;
    for (int i = tid; i < FIN * H; i += 256) sWp[i] = Wp[i];
    for (int i = tid; i < H * H; i += 256) sWm[i] = Wm[i];
    int nb = blockIdx.x * 8;
    int nl = tid >> 5, j = tid & 31;
    int n = nb + nl;
    if (n < NN) sx[nl][j] = x[(size_t)n * FIN + j];
    __syncthreads();
    float acc = 0.f;
#pragma unroll
    for (int k = 0; k < FIN; ++k) acc += sx[nl][k] * sWp[k * H + j];
    sh[nl][j] = acc;
    if (n < NN) h1[(size_t)n * H + j] = acc;
    __syncthreads();
    float acc2 = 0.f;
#pragma unroll
    for (int k = 0; k < H; ++k) acc2 += sh[nl][k] * sWm[k * H + j];
    if (n < NN) m1[(size_t)n * H + j] = acc2;
}

// ---------------- K2: edge gather/scale/scatter-add, F=32 ----------------
__global__ __launch_bounds__(256) void k2_edge32(const int* __restrict__ ei,
                                                 const float* __restrict__ ew,
                                                 const float* __restrict__ msg,
                                                 float* __restrict__ agg) {
    int e = blockIdx.x * 256 + threadIdx.x;
    if (e >= NE) return;
    int s = ei[e], d = ei[NE + e];
    float w = ew[e];
    const float4* ms = (const float4*)(msg + (size_t)s * H);
    float* ad = agg + (size_t)d * H;
#pragma unroll
    for (int i = 0; i < 8; ++i) {
        float4 v = ms[i];
        atomicAdd(ad + 4 * i + 0, v.x * w);
        atomicAdd(ad + 4 * i + 1, v.y * w);
        atomicAdd(ad + 4 * i + 2, v.z * w);
        atomicAdd(ad + 4 * i + 3, v.w * w);
    }
}

// ---------------- K3: GRUCell(H=32) + relu, thread-per-node ----------------
__global__ __launch_bounds__(256) void k3_gru1(const float* __restrict__ agg,
                                               const float* __restrict__ h1,
                                               const float* __restrict__ wih,
                                               const float* __restrict__ whh,
                                               const float* __restrict__ bih,
                                               const float* __restrict__ bhh,
                                               float* __restrict__ out) {
    int n = blockIdx.x * 256 + threadIdx.x;
    if (n >= NN) return;
    float a[H], h[H];
    const float4* ap = (const float4*)(agg + (size_t)n * H);
    const float4* hp = (const float4*)(h1 + (size_t)n * H);
#pragma unroll
    for (int i = 0; i < 8; ++i) {
        ((float4*)a)[i] = ap[i];
        ((float4*)h)[i] = hp[i];
    }
    float4* op = (float4*)(out + (size_t)n * H);
    for (int j4 = 0; j4 < 8; ++j4) {  // rolled: weight idx stays wave-uniform
        float v[4];
#pragma unroll
        for (int jj = 0; jj < 4; ++jj) {
            int j = j4 * 4 + jj;
            float ir = bih[j], iz = bih[H + j], in_ = bih[2 * H + j];
            float hr = bhh[j], hz = bhh[H + j], hn = bhh[2 * H + j];
#pragma unroll
            for (int k = 0; k < H; ++k) {
                float ak = a[k], hk = h[k];
                ir += wih[j * H + k] * ak;
                iz += wih[(H + j) * H + k] * ak;
                in_ += wih[(2 * H + j) * H + k] * ak;
                hr += whh[j * H + k] * hk;
                hz += whh[(H + j) * H + k] * hk;
                hn += whh[(2 * H + j) * H + k] * hk;
            }
            float r = sigm_(ir + hr);
            float z = sigm_(iz + hz);
            float ng = tanh_(in_ + r * hn);
            float hj = h1[(size_t)n * H + j];  // dynamic j: global (L1-hot), avoids reg-spill
            float o = (1.f - z) * ng + z * hj;
            v[jj] = fmaxf(o, 0.f);
        }
        op[j4] = make_float4(v[0], v[1], v[2], v[3]);
    }
}

// ---------------- K4: h2 = hrelu @ W2p ; m2 = h2 @ W2m ----------------
__global__ __launch_bounds__(320) void k4_proj2(const float* __restrict__ hin,
                                                const float* __restrict__ Wp,
                                                const float* __restrict__ Wm,
                                                float* __restrict__ h2,
                                                float* __restrict__ m2) {
    __shared__ float sWp[FIN * NC];
    __shared__ float sWm[NC * NC];
    __shared__ float shn[8][FIN];
    __shared__ float sh2[8][NC];
    int tid = threadIdx.x;
    for (int i = tid; i < FIN * NC; i += 320) sWp[i] = Wp[i];
    for (int i = tid; i < NC * NC; i += 320) sWm[i] = Wm[i];
    int nb = blockIdx.x * 8;
    if (tid < 256) {
        int r = tid >> 5, c = tid & 31;
        shn[r][c] = hin[(size_t)(nb + r) * FIN + c];
    }
    __syncthreads();
    int nl = tid / NC, j = tid % NC;
    int n = nb + nl;
    float acc = 0.f;
#pragma unroll
    for (int k = 0; k < FIN; ++k) acc += shn[nl][k] * sWp[k * NC + j];
    h2[(size_t)n * NC + j] = acc;
    sh2[nl][j] = acc;
    __syncthreads();
    float acc2 = 0.f;
#pragma unroll
    for (int k = 0; k < NC; ++k) acc2 += sh2[nl][k] * sWm[k * NC + j];
    m2[(size_t)n * NC + j] = acc2;
}

// ---------------- K5: edge gather/scale/scatter-add, F=40 ----------------
__global__ __launch_bounds__(256) void k5_edge40(const int* __restrict__ ei,
                                                 const float* __restrict__ ew,
                                                 const float* __restrict__ msg,
                                                 float* __restrict__ agg) {
    int e = blockIdx.x * 256 + threadIdx.x;
    if (e >= NE) return;
    int s = ei[e], d = ei[NE + e];
    float w = ew[e];
    const float4* ms = (const float4*)(msg + (size_t)s * NC);
    float* ad = agg + (size_t)d * NC;
#pragma unroll
    for (int i = 0; i < 10; ++i) {
        float4 v = ms[i];
        atomicAdd(ad + 4 * i + 0, v.x * w);
        atomicAdd(ad + 4 * i + 1, v.y * w);
        atomicAdd(ad + 4 * i + 2, v.z * w);
        atomicAdd(ad + 4 * i + 3, v.w * w);
    }
}

// ---------------- K6: GRUCell(C=40) + log_softmax, thread-per-node ----------------
__global__ __launch_bounds__(256) void k6_gru2(float* __restrict__ agg,  // also scratch
                                               const float* __restrict__ h2,
                                               const float* __restrict__ wih,
                                               const float* __restrict__ whh,
                                               const float* __restrict__ bih,
                                               const float* __restrict__ bhh,
                                               float* __restrict__ out) {
    int n = blockIdx.x * 256 + threadIdx.x;
    if (n >= NN) return;
    float a[NC], h[NC];
    const float4* ap = (const float4*)(agg + (size_t)n * NC);
    const float4* hp = (const float4*)(h2 + (size_t)n * NC);
#pragma unroll
    for (int i = 0; i < 10; ++i) {
        ((float4*)a)[i] = ap[i];
        ((float4*)h)[i] = hp[i];
    }
    float4* sc = (float4*)(agg + (size_t)n * NC);  // agg row dead now -> scratch
    for (int j4 = 0; j4 < 10; ++j4) {
        float v[4];
#pragma unroll
        for (int jj = 0; jj < 4; ++jj) {
            int j = j4 * 4 + jj;
            float ir = bih[j], iz = bih[NC + j], in_ = bih[2 * NC + j];
            float hr = bhh[j], hz = bhh[NC + j], hn = bhh[2 * NC + j];
#pragma unroll
            for (int k = 0; k < NC; ++k) {
                float ak = a[k], hk = h[k];
                ir += wih[j * NC + k] * ak;
                iz += wih[(NC + j) * NC + k] * ak;
                in_ += wih[(2 * NC + j) * NC + k] * ak;
                hr += whh[j * NC + k] * hk;
                hz += whh[(NC + j) * NC + k] * hk;
                hn += whh[(2 * NC + j) * NC + k] * hk;
            }
            float r = sigm_(ir + hr);
            float z = sigm_(iz + hz);
            float ng = tanh_(in_ + r * hn);
            float hj = h2[(size_t)n * NC + j];
            v[jj] = (1.f - z) * ng + z * hj;
        }
        sc[j4] = make_float4(v[0], v[1], v[2], v[3]);
    }
    // log_softmax over the 40 scratch values (same-thread RAW through cache: safe)
    float o[NC];
#pragma unroll
    for (int i = 0; i < 10; ++i) ((float4*)o)[i] = sc[i];
    float m = o[0];
#pragma unroll
    for (int j = 1; j < NC; ++j) m = fmaxf(m, o[j]);
    float s = 0.f;
#pragma unroll
    for (int j = 0; j < NC; ++j) s += __expf(o[j] - m);
    float ls = m + __logf(s);
    float4* op = (float4*)(out + (size_t)n * NC);
#pragma unroll
    for (int i = 0; i < 10; ++i) {
        float4 t = ((float4*)o)[i];
        op[i] = make_float4(t.x - ls, t.y - ls, t.z - ls, t.w - ls);
    }
}

extern "C" void kernel_launch(void* const* d_in, const int* in_sizes, int n_in,
                              void* d_out, int out_size, void* d_ws, size_t ws_size,
                              hipStream_t stream) {
    const float* x = (const float*)d_in[0];
    const int* ei = (const int*)d_in[1];
    const float* ew = (const float*)d_in[2];
    const float* W1p = (const float*)d_in[3];
    const float* W1m = (const float*)d_in[4];
    const float* g1wih = (const float*)d_in[5];
    const float* g1whh = (const float*)d_in[6];
    const float* g1bih = (const float*)d_in[7];
    const float* g1bhh = (const float*)d_in[8];
    const float* W2p = (const float*)d_in[9];
    const float* W2m = (const float*)d_in[10];
    const float* g2wih = (const float*)d_in[11];
    const float* g2whh = (const float*)d_in[12];
    const float* g2bih = (const float*)d_in[13];
    const float* g2bhh = (const float*)d_in[14];
    float* ws = (float*)d_ws;

    // lifetime-overlapped workspace (floats):
    float* h1 = ws + 0;              // [N,32]   live k1..k3
    float* m1 = ws + 4000000;        // [N,32]   live k1..k2
    float* agg1 = ws + 8000000;      // [N,32]   live k2..k3
    float* hrelu = ws + 12000000;    // [N,32]   live k3..k4
    float* h2 = ws + 0;              // [N,40]   live k4..k6 (overlays dead h1)
    float* m2 = ws + 4000000;        // [N,40]   live k4..k5 (overlays dead m1)
    float* agg2 = ws + 8000000;      // [N,40]   live k5..k6 (overlays dead agg1)
    float* out = (float*)d_out;

    k1_proj<<<(NN + 7) / 8, 256, 0, stream>>>(x, W1p, W1m, h1, m1);
    hipMemsetAsync(agg1, 0, (size_t)NN * H * sizeof(float), stream);
    k2_edge32<<<(NE + 255) / 256, 256, 0, stream>>>(ei, ew, m1, agg1);
    k3_gru1<<<(NN + 255) / 256, 256, 0, stream>>>(agg1, h1, g1wih, g1whh, g1bih, g1bhh, hrelu);
    k4_proj2<<<(NN + 7) / 8, 320, 0, stream>>>(hrelu, W2p, W2m, h2, m2);
    hipMemsetAsync(agg2, 0, (size_t)NN * NC * sizeof(float), stream);
    k5_edge40<<<(NE + 255) / 256, 256, 0, stream>>>(ei, ew, m2, agg2);
    k6_gru2<<<(NN + 255) / 256, 256, 0, stream>>>(agg2, h2, g2wih, g2whh, g2bih, g2bhh, out);
}

// Round 2
// 1146.980 us; speedup vs baseline: 6.8933x; 6.8933x over previous
//
#include <hip/hip_runtime.h>
#include <math.h>

#define NN 100000
#define NE 2000000
#define FIN 32
#define H 32
#define NC 40
#define SCAN_CHUNK 1024
#define NB_SCAN ((NN + SCAN_CHUNK - 1) / SCAN_CHUNK)  // 98

__device__ __forceinline__ float sigm_(float x) {
    return 1.0f / (1.0f + __expf(-x));
}
__device__ __forceinline__ float tanh_(float x) {
    x = fminf(fmaxf(x, -20.0f), 20.0f);
    float e = __expf(2.0f * x);
    return (e - 1.0f) / (e + 1.0f);
}

// ---------- CSR build: histogram by dst ----------
__global__ __launch_bounds__(256) void k_hist(const int* __restrict__ ei,
                                              int* __restrict__ counts) {
    int e = blockIdx.x * 256 + threadIdx.x;
    if (e < NE) atomicAdd(&counts[ei[NE + e]], 1);
}

// ---------- scan step 1: per-1024-chunk exclusive scan + block sums ----------
__global__ __launch_bounds__(256) void k_scan1(const int* __restrict__ counts,
                                               int* __restrict__ offsets,
                                               int* __restrict__ bsums) {
    __shared__ int s[256];
    int t = threadIdx.x, b = blockIdx.x;
    int base = b * SCAN_CHUNK + t * 4;
    int c0 = (base + 0 < NN) ? counts[base + 0] : 0;
    int c1 = (base + 1 < NN) ? counts[base + 1] : 0;
    int c2 = (base + 2 < NN) ? counts[base + 2] : 0;
    int c3 = (base + 3 < NN) ? counts[base + 3] : 0;
    int local = c0 + c1 + c2 + c3;
    s[t] = local;
    __syncthreads();
    for (int off = 1; off < 256; off <<= 1) {
        int v = (t >= off) ? s[t - off] : 0;
        __syncthreads();
        s[t] += v;
        __syncthreads();
    }
    int excl = s[t] - local;
    if (t == 255) bsums[b] = s[255];
    if (base + 0 < NN) offsets[base + 0] = excl;
    if (base + 1 < NN) offsets[base + 1] = excl + c0;
    if (base + 2 < NN) offsets[base + 2] = excl + c0 + c1;
    if (base + 3 < NN) offsets[base + 3] = excl + c0 + c1 + c2;
}

// ---------- scan step 2: single-block exclusive scan of 98 block sums ----------
__global__ __launch_bounds__(128) void k_scan2(int* __restrict__ bsums) {
    __shared__ int s[128];
    int t = threadIdx.x;
    int v = (t < NB_SCAN) ? bsums[t] : 0;
    s[t] = v;
    __syncthreads();
    for (int off = 1; off < 128; off <<= 1) {
        int u = (t >= off) ? s[t - off] : 0;
        __syncthreads();
        s[t] += u;
        __syncthreads();
    }
    if (t < NB_SCAN) bsums[t] = s[t] - v;  // exclusive
}

// ---------- scan step 3: add block bases; init cursor ----------
__global__ __launch_bounds__(256) void k_scan3(const int* __restrict__ bsums,
                                               int* __restrict__ offsets,
                                               int* __restrict__ cursor) {
    int i = blockIdx.x * 256 + threadIdx.x;
    if (i < NN) {
        int v = offsets[i] + bsums[i / SCAN_CHUNK];
        offsets[i] = v;
        cursor[i] = v;
    }
    if (i == 0) offsets[NN] = NE;
}

// ---------- counting-sort fill: edge records sorted by dst ----------
__global__ __launch_bounds__(256) void k_fill(const int* __restrict__ ei,
                                              const float* __restrict__ ew,
                                              int* __restrict__ cursor,
                                              int* __restrict__ esrc,
                                              float* __restrict__ ews) {
    int e = blockIdx.x * 256 + threadIdx.x;
    if (e >= NE) return;
    int d = ei[NE + e];
    int pos = atomicAdd(&cursor[d], 1);
    esrc[pos] = ei[e];
    ews[pos] = ew[e];
}

// ---------- precompute Wc = Wm @ wih^T for both layers ----------
// Wc1: [H][3H] row-major; Wc2: [NC][3NC]
__global__ __launch_bounds__(256) void k_wc(const float* __restrict__ W1m,
                                            const float* __restrict__ wih1,
                                            const float* __restrict__ W2m,
                                            const float* __restrict__ wih2,
                                            float* __restrict__ Wc1,
                                            float* __restrict__ Wc2) {
    int i = blockIdx.x * 256 + threadIdx.x;
    if (i < H * 3 * H) {
        int k = i / (3 * H), g = i % (3 * H);
        float acc = 0.f;
#pragma unroll
        for (int t = 0; t < H; ++t) acc += W1m[k * H + t] * wih1[g * H + t];
        Wc1[i] = acc;
    } else if (i < H * 3 * H + NC * 3 * NC) {
        int j = i - H * 3 * H;
        int k = j / (3 * NC), g = j % (3 * NC);
        float acc = 0.f;
#pragma unroll
        for (int t = 0; t < NC; ++t) acc += W2m[k * NC + t] * wih2[g * NC + t];
        Wc2[j] = acc;
    }
}

// ---------- K1: h1 = x @ W1p ----------
__global__ __launch_bounds__(256) void k1_proj(const float* __restrict__ x,
                                               const float* __restrict__ Wp,
                                               float* __restrict__ h1) {
    __shared__ float sWp[FIN * H];
    __shared__ float sx[8][FIN];
    int tid = threadIdx.x;
    for (int i = tid; i < FIN * H; i += 256) sWp[i] = Wp[i];
    int nb = blockIdx.x * 8;
    int nl = tid >> 5, j = tid & 31;
    int n = nb + nl;
    if (n < NN) sx[nl][j] = x[(size_t)n * FIN + j];
    __syncthreads();
    float acc = 0.f;
#pragma unroll
    for (int k = 0; k < FIN; ++k) acc += sx[nl][k] * sWp[k * H + j];
    if (n < NN) h1[(size_t)n * H + j] = acc;
}

// ---------- K4: h2 = hrelu @ W2p ----------
__global__ __launch_bounds__(320) void k4_proj2(const float* __restrict__ hin,
                                                const float* __restrict__ Wp,
                                                float* __restrict__ h2) {
    __shared__ float sWp[FIN * NC];
    __shared__ float shn[8][FIN];
    int tid = threadIdx.x;
    for (int i = tid; i < FIN * NC; i += 320) sWp[i] = Wp[i];
    int nb = blockIdx.x * 8;
    if (tid < 256) {
        int r = tid >> 5, c = tid & 31;
        shn[r][c] = hin[(size_t)(nb + r) * FIN + c];
    }
    __syncthreads();
    int nl = tid / NC, j = tid % NC;
    int n = nb + nl;
    float acc = 0.f;
#pragma unroll
    for (int k = 0; k < FIN; ++k) acc += shn[nl][k] * sWp[k * NC + j];
    if (n < NN) h2[(size_t)n * NC + j] = acc;
}

// ---------- aggregation: agg[d] = sum over CSR edges of w * h[src], no atomics ----------
template <int F>
__global__ __launch_bounds__(256) void k_agg(const int* __restrict__ offsets,
                                             const int* __restrict__ esrc,
                                             const float* __restrict__ ews,
                                             const float* __restrict__ h,
                                             float* __restrict__ agg) {
    int idx = blockIdx.x * 256 + threadIdx.x;
    int n = idx / F, f = idx % F;
    if (n >= NN) return;
    int s0 = offsets[n], s1 = offsets[n + 1];
    float acc = 0.f;
    for (int e = s0; e < s1; ++e) {
        acc += ews[e] * h[(size_t)esrc[e] * F + f];
    }
    agg[(size_t)n * F + f] = acc;
}

// ---------- K3: GRU layer1 (input folded via Wc1) + relu ----------
__global__ __launch_bounds__(256) void k3_gru1(const float* __restrict__ aggh,
                                               const float* __restrict__ h1,
                                               const float* __restrict__ Wc,   // [H][3H]
                                               const float* __restrict__ whh,  // [3H][H]
                                               const float* __restrict__ bih,
                                               const float* __restrict__ bhh,
                                               float* __restrict__ out) {
    int n = blockIdx.x * 256 + threadIdx.x;
    if (n >= NN) return;
    float a[H], h[H];
    const float4* ap = (const float4*)(aggh + (size_t)n * H);
    const float4* hp = (const float4*)(h1 + (size_t)n * H);
#pragma unroll
    for (int i = 0; i < 8; ++i) {
        ((float4*)a)[i] = ap[i];
        ((float4*)h)[i] = hp[i];
    }
    float4* op = (float4*)(out + (size_t)n * H);
    for (int j4 = 0; j4 < 8; ++j4) {  // rolled: weight idx stays wave-uniform
        float v[4];
#pragma unroll
        for (int jj = 0; jj < 4; ++jj) {
            int j = j4 * 4 + jj;
            float ir = bih[j], iz = bih[H + j], in_ = bih[2 * H + j];
            float hr = bhh[j], hz = bhh[H + j], hn = bhh[2 * H + j];
#pragma unroll
            for (int k = 0; k < H; ++k) {
                float ak = a[k], hk = h[k];
                ir += Wc[k * 3 * H + j] * ak;
                iz += Wc[k * 3 * H + H + j] * ak;
                in_ += Wc[k * 3 * H + 2 * H + j] * ak;
                hr += whh[j * H + k] * hk;
                hz += whh[(H + j) * H + k] * hk;
                hn += whh[(2 * H + j) * H + k] * hk;
            }
            float r = sigm_(ir + hr);
            float z = sigm_(iz + hz);
            float ng = tanh_(in_ + r * hn);
            float hj = h1[(size_t)n * H + j];  // dynamic j: global (L1-hot), avoids reg-spill
            float o = (1.f - z) * ng + z * hj;
            v[jj] = fmaxf(o, 0.f);
        }
        op[j4] = make_float4(v[0], v[1], v[2], v[3]);
    }
}

// ---------- K6: GRU layer2 (folded via Wc2) + log_softmax ----------
__global__ __launch_bounds__(256) void k6_gru2(float* __restrict__ aggh,  // also scratch
                                               const float* __restrict__ h2,
                                               const float* __restrict__ Wc,   // [NC][3NC]
                                               const float* __restrict__ whh,  // [3NC][NC]
                                               const float* __restrict__ bih,
                                               const float* __restrict__ bhh,
                                               float* __restrict__ out) {
    int n = blockIdx.x * 256 + threadIdx.x;
    if (n >= NN) return;
    float a[NC], h[NC];
    const float4* ap = (const float4*)(aggh + (size_t)n * NC);
    const float4* hp = (const float4*)(h2 + (size_t)n * NC);
#pragma unroll
    for (int i = 0; i < 10; ++i) {
        ((float4*)a)[i] = ap[i];
        ((float4*)h)[i] = hp[i];
    }
    float4* sc = (float4*)(aggh + (size_t)n * NC);  // agg row dead now -> scratch
    for (int j4 = 0; j4 < 10; ++j4) {
        float v[4];
#pragma unroll
        for (int jj = 0; jj < 4; ++jj) {
            int j = j4 * 4 + jj;
            float ir = bih[j], iz = bih[NC + j], in_ = bih[2 * NC + j];
            float hr = bhh[j], hz = bhh[NC + j], hn = bhh[2 * NC + j];
#pragma unroll
            for (int k = 0; k < NC; ++k) {
                float ak = a[k], hk = h[k];
                ir += Wc[k * 3 * NC + j] * ak;
                iz += Wc[k * 3 * NC + NC + j] * ak;
                in_ += Wc[k * 3 * NC + 2 * NC + j] * ak;
                hr += whh[j * NC + k] * hk;
                hz += whh[(NC + j) * NC + k] * hk;
                hn += whh[(2 * NC + j) * NC + k] * hk;
            }
            float r = sigm_(ir + hr);
            float z = sigm_(iz + hz);
            float ng = tanh_(in_ + r * hn);
            float hj = h2[(size_t)n * NC + j];
            v[jj] = (1.f - z) * ng + z * hj;
        }
        sc[j4] = make_float4(v[0], v[1], v[2], v[3]);
    }
    float o[NC];
#pragma unroll
    for (int i = 0; i < 10; ++i) ((float4*)o)[i] = sc[i];
    float m = o[0];
#pragma unroll
    for (int j = 1; j < NC; ++j) m = fmaxf(m, o[j]);
    float s = 0.f;
#pragma unroll
    for (int j = 0; j < NC; ++j) s += __expf(o[j] - m);
    float ls = m + __logf(s);
    float4* op = (float4*)(out + (size_t)n * NC);
#pragma unroll
    for (int i = 0; i < 10; ++i) {
        float4 t = ((float4*)o)[i];
        op[i] = make_float4(t.x - ls, t.y - ls, t.z - ls, t.w - ls);
    }
}

extern "C" void kernel_launch(void* const* d_in, const int* in_sizes, int n_in,
                              void* d_out, int out_size, void* d_ws, size_t ws_size,
                              hipStream_t stream) {
    const float* x = (const float*)d_in[0];
    const int* ei = (const int*)d_in[1];
    const float* ew = (const float*)d_in[2];
    const float* W1p = (const float*)d_in[3];
    const float* W1m = (const float*)d_in[4];
    const float* g1wih = (const float*)d_in[5];
    const float* g1whh = (const float*)d_in[6];
    const float* g1bih = (const float*)d_in[7];
    const float* g1bhh = (const float*)d_in[8];
    const float* W2p = (const float*)d_in[9];
    const float* W2m = (const float*)d_in[10];
    const float* g2wih = (const float*)d_in[11];
    const float* g2whh = (const float*)d_in[12];
    const float* g2bih = (const float*)d_in[13];
    const float* g2bhh = (const float*)d_in[14];
    float* ws = (float*)d_ws;

    // workspace layout (floats) — 62 MB total, lifetime-overlapped:
    float* A = ws + 0;               // h1 [N,32] (k1..k3) then h2 [N,40] (k4..k6)
    float* B = ws + 4000000;         // aggh1 [N,32] then aggh2 [N,40]
    float* C = ws + 8000000;         // hrelu [N,32]
    int* esrc = (int*)(ws + 11200000);     // 2M
    float* ews = ws + 13200000;            // 2M
    int* offs = (int*)(ws + 15200000);     // 100001
    int* cnts = (int*)(ws + 15300004);     // 100000
    int* curs = (int*)(ws + 15400004);     // 100000
    int* bsum = (int*)(ws + 15500004);     // 128
    float* Wc1 = ws + 15500136;            // 3072
    float* Wc2 = ws + 15503208;            // 4800
    float* out = (float*)d_out;

    // ---- CSR build (shared by both layers) ----
    hipMemsetAsync(cnts, 0, (size_t)NN * sizeof(int), stream);
    k_hist<<<(NE + 255) / 256, 256, 0, stream>>>(ei, cnts);
    k_scan1<<<NB_SCAN, 256, 0, stream>>>(cnts, offs, bsum);
    k_scan2<<<1, 128, 0, stream>>>(bsum);
    k_scan3<<<(NN + 255) / 256, 256, 0, stream>>>(bsum, offs, curs);
    k_fill<<<(NE + 255) / 256, 256, 0, stream>>>(ei, ew, curs, esrc, ews);
    k_wc<<<(H * 3 * H + NC * 3 * NC + 255) / 256, 256, 0, stream>>>(W1m, g1wih, W2m, g2wih, Wc1, Wc2);

    // ---- layer 1 ----
    k1_proj<<<(NN + 7) / 8, 256, 0, stream>>>(x, W1p, A);
    k_agg<32><<<(NN * 32 + 255) / 256, 256, 0, stream>>>(offs, esrc, ews, A, B);
    k3_gru1<<<(NN + 255) / 256, 256, 0, stream>>>(B, A, Wc1, g1whh, g1bih, g1bhh, C);

    // ---- layer 2 ----
    k4_proj2<<<(NN + 7) / 8, 320, 0, stream>>>(C, W2p, A);
    k_agg<40><<<(NN * 40 + 255) / 256, 256, 0, stream>>>(offs, esrc, ews, A, B);
    k6_gru2<<<(NN + 255) / 256, 256, 0, stream>>>(B, A, Wc2, g2whh, g2bih, g2bhh, out);
}

// Round 3
// 704.665 us; speedup vs baseline: 11.2202x; 1.6277x over previous
//
#include <hip/hip_runtime.h>
#include <math.h>

#define NN 100000
#define NE 2000000
#define FIN 32
#define H 32
#define NC 40
#define SCAN_CHUNK 1024
#define NB_SCAN ((NN + SCAN_CHUNK - 1) / SCAN_CHUNK)  // 98

__device__ __forceinline__ float sigm_(float x) {
    return 1.0f / (1.0f + __expf(-x));
}
__device__ __forceinline__ float tanh_(float x) {
    x = fminf(fmaxf(x, -20.0f), 20.0f);
    float e = __expf(2.0f * x);
    return (e - 1.0f) / (e + 1.0f);
}

// ---------- CSR build: histogram by dst ----------
__global__ __launch_bounds__(256) void k_hist(const int* __restrict__ ei,
                                              int* __restrict__ counts) {
    int e = blockIdx.x * 256 + threadIdx.x;
    if (e < NE) atomicAdd(&counts[ei[NE + e]], 1);
}

// ---------- scan step 1 ----------
__global__ __launch_bounds__(256) void k_scan1(const int* __restrict__ counts,
                                               int* __restrict__ offsets,
                                               int* __restrict__ bsums) {
    __shared__ int s[256];
    int t = threadIdx.x, b = blockIdx.x;
    int base = b * SCAN_CHUNK + t * 4;
    int c0 = (base + 0 < NN) ? counts[base + 0] : 0;
    int c1 = (base + 1 < NN) ? counts[base + 1] : 0;
    int c2 = (base + 2 < NN) ? counts[base + 2] : 0;
    int c3 = (base + 3 < NN) ? counts[base + 3] : 0;
    int local = c0 + c1 + c2 + c3;
    s[t] = local;
    __syncthreads();
    for (int off = 1; off < 256; off <<= 1) {
        int v = (t >= off) ? s[t - off] : 0;
        __syncthreads();
        s[t] += v;
        __syncthreads();
    }
    int excl = s[t] - local;
    if (t == 255) bsums[b] = s[255];
    if (base + 0 < NN) offsets[base + 0] = excl;
    if (base + 1 < NN) offsets[base + 1] = excl + c0;
    if (base + 2 < NN) offsets[base + 2] = excl + c0 + c1;
    if (base + 3 < NN) offsets[base + 3] = excl + c0 + c1 + c2;
}

// ---------- scan step 2 ----------
__global__ __launch_bounds__(128) void k_scan2(int* __restrict__ bsums) {
    __shared__ int s[128];
    int t = threadIdx.x;
    int v = (t < NB_SCAN) ? bsums[t] : 0;
    s[t] = v;
    __syncthreads();
    for (int off = 1; off < 128; off <<= 1) {
        int u = (t >= off) ? s[t - off] : 0;
        __syncthreads();
        s[t] += u;
        __syncthreads();
    }
    if (t < NB_SCAN) bsums[t] = s[t] - v;  // exclusive
}

// ---------- scan step 3 ----------
__global__ __launch_bounds__(256) void k_scan3(const int* __restrict__ bsums,
                                               int* __restrict__ offsets,
                                               int* __restrict__ cursor) {
    int i = blockIdx.x * 256 + threadIdx.x;
    if (i < NN) {
        int v = offsets[i] + bsums[i / SCAN_CHUNK];
        offsets[i] = v;
        cursor[i] = v;
    }
    if (i == 0) offsets[NN] = NE;
}

// ---------- counting-sort fill ----------
__global__ __launch_bounds__(256) void k_fill(const int* __restrict__ ei,
                                              const float* __restrict__ ew,
                                              int* __restrict__ cursor,
                                              int* __restrict__ esrc,
                                              float* __restrict__ ews) {
    int e = blockIdx.x * 256 + threadIdx.x;
    if (e >= NE) return;
    int d = ei[NE + e];
    int pos = atomicAdd(&cursor[d], 1);
    esrc[pos] = ei[e];
    ews[pos] = ew[e];
}

// ---------- precompute Wc = Wm @ wih^T (k-major) and WhhT (k-major transpose of whh) ----------
__global__ __launch_bounds__(256) void k_wc(const float* __restrict__ W1m,
                                            const float* __restrict__ wih1,
                                            const float* __restrict__ W2m,
                                            const float* __restrict__ wih2,
                                            const float* __restrict__ whh1,
                                            const float* __restrict__ whh2,
                                            float* __restrict__ Wc1,
                                            float* __restrict__ Wc2,
                                            float* __restrict__ WhT1,
                                            float* __restrict__ WhT2) {
    int i = blockIdx.x * 256 + threadIdx.x;
    if (i < H * 3 * H) {  // Wc1[k*96 + c]
        int k = i / (3 * H), g = i % (3 * H);
        float acc = 0.f;
#pragma unroll
        for (int t = 0; t < H; ++t) acc += W1m[k * H + t] * wih1[g * H + t];
        Wc1[i] = acc;
    } else if (i < H * 3 * H + NC * 3 * NC) {  // Wc2[k*120 + c]
        int j = i - H * 3 * H;
        int k = j / (3 * NC), g = j % (3 * NC);
        float acc = 0.f;
#pragma unroll
        for (int t = 0; t < NC; ++t) acc += W2m[k * NC + t] * wih2[g * NC + t];
        Wc2[j] = acc;
    } else if (i < H * 3 * H + NC * 3 * NC + H * 3 * H) {  // WhT1[k*96 + c] = whh1[c*32 + k]
        int t = i - (H * 3 * H + NC * 3 * NC);
        int k = t / (3 * H), c = t % (3 * H);
        WhT1[t] = whh1[c * H + k];
    } else if (i < H * 3 * H + NC * 3 * NC + H * 3 * H + NC * 3 * NC) {
        int t = i - (H * 3 * H + NC * 3 * NC + H * 3 * H);
        int k = t / (3 * NC), c = t % (3 * NC);
        WhT2[t] = whh2[c * NC + k];
    }
}

// ---------- K1: h1 = x @ W1p ----------
__global__ __launch_bounds__(256) void k1_proj(const float* __restrict__ x,
                                               const float* __restrict__ Wp,
                                               float* __restrict__ h1) {
    __shared__ float sWp[FIN * H];
    __shared__ float sx[8][FIN];
    int tid = threadIdx.x;
    for (int i = tid; i < FIN * H; i += 256) sWp[i] = Wp[i];
    int nb = blockIdx.x * 8;
    int nl = tid >> 5, j = tid & 31;
    int n = nb + nl;
    if (n < NN) sx[nl][j] = x[(size_t)n * FIN + j];
    __syncthreads();
    float acc = 0.f;
#pragma unroll
    for (int k = 0; k < FIN; ++k) acc += sx[nl][k] * sWp[k * H + j];
    if (n < NN) h1[(size_t)n * H + j] = acc;
}

// ---------- K4: h2 = hrelu @ W2p ----------
__global__ __launch_bounds__(320) void k4_proj2(const float* __restrict__ hin,
                                                const float* __restrict__ Wp,
                                                float* __restrict__ h2) {
    __shared__ float sWp[FIN * NC];
    __shared__ float shn[8][FIN];
    int tid = threadIdx.x;
    for (int i = tid; i < FIN * NC; i += 320) sWp[i] = Wp[i];
    int nb = blockIdx.x * 8;
    if (tid < 256) {
        int r = tid >> 5, c = tid & 31;
        shn[r][c] = hin[(size_t)(nb + r) * FIN + c];
    }
    __syncthreads();
    int nl = tid / NC, j = tid % NC;
    int n = nb + nl;
    float acc = 0.f;
#pragma unroll
    for (int k = 0; k < FIN; ++k) acc += shn[nl][k] * sWp[k * NC + j];
    if (n < NN) h2[(size_t)n * NC + j] = acc;
}

// ---------- aggregation: agg[d] = sum CSR w * h[src], no atomics ----------
template <int F>
__global__ __launch_bounds__(256) void k_agg(const int* __restrict__ offsets,
                                             const int* __restrict__ esrc,
                                             const float* __restrict__ ews,
                                             const float* __restrict__ h,
                                             float* __restrict__ agg) {
    int idx = blockIdx.x * 256 + threadIdx.x;
    int n = idx / F, f = idx % F;
    if (n >= NN) return;
    int s0 = offsets[n], s1 = offsets[n + 1];
    float acc = 0.f;
    for (int e = s0; e < s1; ++e) {
        acc += ews[e] * h[(size_t)esrc[e] * F + f];
    }
    agg[(size_t)n * F + f] = acc;
}

// ---------- K3: GRU layer1 + relu. block = 32 j-lanes x 8 slots, 4 nodes/thread ----------
__global__ __launch_bounds__(256) void k3_gru1(const float* __restrict__ aggh,
                                               const float* __restrict__ h1,
                                               const float* __restrict__ Wc,   // [32][96] k-major
                                               const float* __restrict__ WhT,  // [32][96] k-major
                                               const float* __restrict__ bih,
                                               const float* __restrict__ bhh,
                                               float* __restrict__ out) {
    __shared__ float sA[1024], sH[1024], sWc[3072], sWT[3072];
    int tid = threadIdx.x;
    int nb = blockIdx.x * 32;
    ((float4*)sA)[tid] = ((const float4*)(aggh + (size_t)nb * H))[tid];
    ((float4*)sH)[tid] = ((const float4*)(h1 + (size_t)nb * H))[tid];
    for (int i = tid; i < 768; i += 256) {
        ((float4*)sWc)[i] = ((const float4*)Wc)[i];
        ((float4*)sWT)[i] = ((const float4*)WhT)[i];
    }
    __syncthreads();
    int j = tid & 31, slot = tid >> 5;
    int r0 = slot * 4;
    float ar[4] = {0, 0, 0, 0}, az[4] = {0, 0, 0, 0}, an[4] = {0, 0, 0, 0};
    float hr[4] = {0, 0, 0, 0}, hz[4] = {0, 0, 0, 0}, hn[4] = {0, 0, 0, 0};
#pragma unroll
    for (int kc = 0; kc < 8; ++kc) {
        float4 a4[4], h4[4];
#pragma unroll
        for (int m = 0; m < 4; ++m) {
            a4[m] = *(const float4*)&sA[(r0 + m) * 32 + kc * 4];
            h4[m] = *(const float4*)&sH[(r0 + m) * 32 + kc * 4];
        }
#pragma unroll
        for (int kk = 0; kk < 4; ++kk) {
            int k = kc * 4 + kk;
            float wr = sWc[k * 96 + j], wz = sWc[k * 96 + 32 + j], wn = sWc[k * 96 + 64 + j];
            float ur = sWT[k * 96 + j], uz = sWT[k * 96 + 32 + j], un = sWT[k * 96 + 64 + j];
#pragma unroll
            for (int m = 0; m < 4; ++m) {
                float ak = ((const float*)&a4[m])[kk];
                float hk = ((const float*)&h4[m])[kk];
                ar[m] += wr * ak; az[m] += wz * ak; an[m] += wn * ak;
                hr[m] += ur * hk; hz[m] += uz * hk; hn[m] += un * hk;
            }
        }
    }
    float b_r = bih[j] + bhh[j];
    float b_z = bih[H + j] + bhh[H + j];
    float bin = bih[2 * H + j];
    float bhn = bhh[2 * H + j];
#pragma unroll
    for (int m = 0; m < 4; ++m) {
        float r = sigm_(ar[m] + hr[m] + b_r);
        float z = sigm_(az[m] + hz[m] + b_z);
        float ng = tanh_(an[m] + bin + r * (hn[m] + bhn));
        float hj = sH[(r0 + m) * 32 + j];
        float o = (1.f - z) * ng + z * hj;
        out[(size_t)(nb + r0 + m) * H + j] = fmaxf(o, 0.f);
    }
}

// ---------- K6: GRU layer2 + log_softmax. block = 40 j-lanes x 8 slots, 4 nodes/thread ----------
__global__ __launch_bounds__(320) void k6_gru2(const float* __restrict__ aggh,
                                               const float* __restrict__ h2,
                                               const float* __restrict__ Wc,   // [40][120] k-major
                                               const float* __restrict__ WhT,  // [40][120] k-major
                                               const float* __restrict__ bih,
                                               const float* __restrict__ bhh,
                                               float* __restrict__ out) {
    // smem: sA[1280] | sH[1280] | sWc[4800] | sWT[4800] | sLs[32]; sOut(32x41) overlays sA(+sH head)
    __shared__ float smem[12192];
    float* sA = smem;
    float* sH = smem + 1280;
    float* sWc = smem + 2560;
    float* sWT = smem + 7360;
    float* sLs = smem + 12160;
    int tid = threadIdx.x;
    int nb = blockIdx.x * 32;
    ((float4*)sA)[tid] = ((const float4*)(aggh + (size_t)nb * NC))[tid];
    ((float4*)sH)[tid] = ((const float4*)(h2 + (size_t)nb * NC))[tid];
    for (int i = tid; i < 1200; i += 320) {
        ((float4*)sWc)[i] = ((const float4*)Wc)[i];
        ((float4*)sWT)[i] = ((const float4*)WhT)[i];
    }
    __syncthreads();
    int j = tid % NC, slot = tid / NC;
    int r0 = slot * 4;
    float ar[4] = {0, 0, 0, 0}, az[4] = {0, 0, 0, 0}, an[4] = {0, 0, 0, 0};
    float hr[4] = {0, 0, 0, 0}, hz[4] = {0, 0, 0, 0}, hn[4] = {0, 0, 0, 0};
#pragma unroll
    for (int kc = 0; kc < 10; ++kc) {
        float4 a4[4], h4[4];
#pragma unroll
        for (int m = 0; m < 4; ++m) {
            a4[m] = *(const float4*)&sA[(r0 + m) * 40 + kc * 4];
            h4[m] = *(const float4*)&sH[(r0 + m) * 40 + kc * 4];
        }
#pragma unroll
        for (int kk = 0; kk < 4; ++kk) {
            int k = kc * 4 + kk;
            float wr = sWc[k * 120 + j], wz = sWc[k * 120 + 40 + j], wn = sWc[k * 120 + 80 + j];
            float ur = sWT[k * 120 + j], uz = sWT[k * 120 + 40 + j], un = sWT[k * 120 + 80 + j];
#pragma unroll
            for (int m = 0; m < 4; ++m) {
                float ak = ((const float*)&a4[m])[kk];
                float hk = ((const float*)&h4[m])[kk];
                ar[m] += wr * ak; az[m] += wz * ak; an[m] += wn * ak;
                hr[m] += ur * hk; hz[m] += uz * hk; hn[m] += un * hk;
            }
        }
    }
    float b_r = bih[j] + bhh[j];
    float b_z = bih[NC + j] + bhh[NC + j];
    float bin = bih[2 * NC + j];
    float bhn = bhh[2 * NC + j];
    float v[4];
#pragma unroll
    for (int m = 0; m < 4; ++m) {
        float r = sigm_(ar[m] + hr[m] + b_r);
        float z = sigm_(az[m] + hz[m] + b_z);
        float ng = tanh_(an[m] + bin + r * (hn[m] + bhn));
        float hj = sH[(r0 + m) * 40 + j];
        v[m] = (1.f - z) * ng + z * hj;
    }
    __syncthreads();  // all reads of sA/sH done before overlay
    float* sOut = smem;  // stride 41 -> conflict-free column reads
#pragma unroll
    for (int m = 0; m < 4; ++m) sOut[(r0 + m) * 41 + j] = v[m];
    __syncthreads();
    if (tid < 32) {
        const float* row = sOut + tid * 41;
        float mx = row[0];
#pragma unroll
        for (int t = 1; t < NC; ++t) mx = fmaxf(mx, row[t]);
        float s = 0.f;
#pragma unroll
        for (int t = 0; t < NC; ++t) s += __expf(row[t] - mx);
        sLs[tid] = mx + __logf(s);
    }
    __syncthreads();
#pragma unroll
    for (int m = 0; m < 4; ++m)
        out[(size_t)(nb + r0 + m) * NC + j] = v[m] - sLs[r0 + m];
}

extern "C" void kernel_launch(void* const* d_in, const int* in_sizes, int n_in,
                              void* d_out, int out_size, void* d_ws, size_t ws_size,
                              hipStream_t stream) {
    const float* x = (const float*)d_in[0];
    const int* ei = (const int*)d_in[1];
    const float* ew = (const float*)d_in[2];
    const float* W1p = (const float*)d_in[3];
    const float* W1m = (const float*)d_in[4];
    const float* g1wih = (const float*)d_in[5];
    const float* g1whh = (const float*)d_in[6];
    const float* g1bih = (const float*)d_in[7];
    const float* g1bhh = (const float*)d_in[8];
    const float* W2p = (const float*)d_in[9];
    const float* W2m = (const float*)d_in[10];
    const float* g2wih = (const float*)d_in[11];
    const float* g2whh = (const float*)d_in[12];
    const float* g2bih = (const float*)d_in[13];
    const float* g2bhh = (const float*)d_in[14];
    float* ws = (float*)d_ws;

    // workspace layout (floats) — lifetime-overlapped, same footprint as round 2:
    float* A = ws + 0;               // h1 [N,32] then h2 [N,40]
    float* B = ws + 4000000;         // aggh1 [N,32] then aggh2 [N,40]
    float* C = ws + 8000000;         // hrelu [N,32]
    int* esrc = (int*)(ws + 11200000);     // 2M
    float* ews = ws + 13200000;            // 2M
    int* offs = (int*)(ws + 15200000);     // 100001
    int* cnts = (int*)(ws + 15300004);     // 100000 (dead after scan1)
    int* curs = (int*)(ws + 15400004);     // 100000 (dead after fill)
    int* bsum = (int*)(ws + 15500004);     // 128
    float* Wc1 = ws + 15500136;            // 3072
    float* Wc2 = ws + 15503208;            // 4800
    float* WhT1 = (float*)(ws + 15300004); // 3072, overlays dead cnts
    float* WhT2 = (float*)(ws + 15400004); // 4800, overlays dead curs
    float* out = (float*)d_out;

    // ---- CSR build (shared by both layers) ----
    hipMemsetAsync(cnts, 0, (size_t)NN * sizeof(int), stream);
    k_hist<<<(NE + 255) / 256, 256, 0, stream>>>(ei, cnts);
    k_scan1<<<NB_SCAN, 256, 0, stream>>>(cnts, offs, bsum);
    k_scan2<<<1, 128, 0, stream>>>(bsum);
    k_scan3<<<(NN + 255) / 256, 256, 0, stream>>>(bsum, offs, curs);
    k_fill<<<(NE + 255) / 256, 256, 0, stream>>>(ei, ew, curs, esrc, ews);
    k_wc<<<(2 * (H * 3 * H + NC * 3 * NC) + 255) / 256, 256, 0, stream>>>(
        W1m, g1wih, W2m, g2wih, g1whh, g2whh, Wc1, Wc2, WhT1, WhT2);

    // ---- layer 1 ----
    k1_proj<<<(NN + 7) / 8, 256, 0, stream>>>(x, W1p, A);
    k_agg<32><<<(NN * 32 + 255) / 256, 256, 0, stream>>>(offs, esrc, ews, A, B);
    k3_gru1<<<NN / 32, 256, 0, stream>>>(B, A, Wc1, WhT1, g1bih, g1bhh, C);

    // ---- layer 2 ----
    k4_proj2<<<(NN + 7) / 8, 320, 0, stream>>>(C, W2p, A);
    k_agg<40><<<(NN * 40 + 255) / 256, 256, 0, stream>>>(offs, esrc, ews, A, B);
    k6_gru2<<<NN / 32, 320, 0, stream>>>(B, A, Wc2, WhT2, g2bih, g2bhh, out);
}

// Round 4
// 465.217 us; speedup vs baseline: 16.9953x; 1.5147x over previous
//
#include <hip/hip_runtime.h>
#include <math.h>

#define NN 100000
#define NE 2000000
#define FIN 32
#define H 32
#define NC 40
#define SCAN_CHUNK 1024
#define NB_SCAN ((NN + SCAN_CHUNK - 1) / SCAN_CHUNK)  // 98

__device__ __forceinline__ float sigm_(float x) {
    return 1.0f / (1.0f + __expf(-x));
}
__device__ __forceinline__ float tanh_(float x) {
    x = fminf(fmaxf(x, -20.0f), 20.0f);
    float e = __expf(2.0f * x);
    return (e - 1.0f) / (e + 1.0f);
}

// ---------- CSR build: histogram by dst + rank capture ----------
__global__ __launch_bounds__(256) void k_hist(const int* __restrict__ ei,
                                              int* __restrict__ counts,
                                              int* __restrict__ rank) {
    int e = blockIdx.x * 256 + threadIdx.x;
    if (e < NE) rank[e] = atomicAdd(&counts[ei[NE + e]], 1);
}

// ---------- scan step 1 ----------
__global__ __launch_bounds__(256) void k_scan1(const int* __restrict__ counts,
                                               int* __restrict__ offsets,
                                               int* __restrict__ bsums) {
    __shared__ int s[256];
    int t = threadIdx.x, b = blockIdx.x;
    int base = b * SCAN_CHUNK + t * 4;
    int c0 = (base + 0 < NN) ? counts[base + 0] : 0;
    int c1 = (base + 1 < NN) ? counts[base + 1] : 0;
    int c2 = (base + 2 < NN) ? counts[base + 2] : 0;
    int c3 = (base + 3 < NN) ? counts[base + 3] : 0;
    int local = c0 + c1 + c2 + c3;
    s[t] = local;
    __syncthreads();
    for (int off = 1; off < 256; off <<= 1) {
        int v = (t >= off) ? s[t - off] : 0;
        __syncthreads();
        s[t] += v;
        __syncthreads();
    }
    int excl = s[t] - local;
    if (t == 255) bsums[b] = s[255];
    if (base + 0 < NN) offsets[base + 0] = excl;
    if (base + 1 < NN) offsets[base + 1] = excl + c0;
    if (base + 2 < NN) offsets[base + 2] = excl + c0 + c1;
    if (base + 3 < NN) offsets[base + 3] = excl + c0 + c1 + c2;
}

// ---------- scan step 2 ----------
__global__ __launch_bounds__(128) void k_scan2(int* __restrict__ bsums) {
    __shared__ int s[128];
    int t = threadIdx.x;
    int v = (t < NB_SCAN) ? bsums[t] : 0;
    s[t] = v;
    __syncthreads();
    for (int off = 1; off < 128; off <<= 1) {
        int u = (t >= off) ? s[t - off] : 0;
        __syncthreads();
        s[t] += u;
        __syncthreads();
    }
    if (t < NB_SCAN) bsums[t] = s[t] - v;  // exclusive
}

// ---------- scan step 3 ----------
__global__ __launch_bounds__(256) void k_scan3(const int* __restrict__ bsums,
                                               int* __restrict__ offsets) {
    int i = blockIdx.x * 256 + threadIdx.x;
    if (i < NN) offsets[i] = offsets[i] + bsums[i / SCAN_CHUNK];
    if (i == 0) offsets[NN] = NE;
}

// ---------- fill: atomic-free, one packed 8B record per edge ----------
__global__ __launch_bounds__(256) void k_fill(const int* __restrict__ ei,
                                              const float* __restrict__ ew,
                                              const int* __restrict__ offs,
                                              const int* __restrict__ rank,
                                              int2* __restrict__ evs) {
    int e = blockIdx.x * 256 + threadIdx.x;
    if (e >= NE) return;
    int d = ei[NE + e];
    int pos = offs[d] + rank[e];
    evs[pos] = make_int2(ei[e], __float_as_int(ew[e]));
}

// ---------- precompute Wc = Wm @ wih^T (k-major) and WhhT (k-major transpose of whh) ----------
__global__ __launch_bounds__(256) void k_wc(const float* __restrict__ W1m,
                                            const float* __restrict__ wih1,
                                            const float* __restrict__ W2m,
                                            const float* __restrict__ wih2,
                                            const float* __restrict__ whh1,
                                            const float* __restrict__ whh2,
                                            float* __restrict__ Wc1,
                                            float* __restrict__ Wc2,
                                            float* __restrict__ WhT1,
                                            float* __restrict__ WhT2) {
    int i = blockIdx.x * 256 + threadIdx.x;
    if (i < H * 3 * H) {  // Wc1[k*96 + c]
        int k = i / (3 * H), g = i % (3 * H);
        float acc = 0.f;
#pragma unroll
        for (int t = 0; t < H; ++t) acc += W1m[k * H + t] * wih1[g * H + t];
        Wc1[i] = acc;
    } else if (i < H * 3 * H + NC * 3 * NC) {  // Wc2[k*120 + c]
        int j = i - H * 3 * H;
        int k = j / (3 * NC), g = j % (3 * NC);
        float acc = 0.f;
#pragma unroll
        for (int t = 0; t < NC; ++t) acc += W2m[k * NC + t] * wih2[g * NC + t];
        Wc2[j] = acc;
    } else if (i < H * 3 * H + NC * 3 * NC + H * 3 * H) {  // WhT1[k*96 + c] = whh1[c*32 + k]
        int t = i - (H * 3 * H + NC * 3 * NC);
        int k = t / (3 * H), c = t % (3 * H);
        WhT1[t] = whh1[c * H + k];
    } else if (i < H * 3 * H + NC * 3 * NC + H * 3 * H + NC * 3 * NC) {
        int t = i - (H * 3 * H + NC * 3 * NC + H * 3 * H);
        int k = t / (3 * NC), c = t % (3 * NC);
        WhT2[t] = whh2[c * NC + k];
    }
}

// ---------- K1: h1 = x @ W1p ----------
__global__ __launch_bounds__(256) void k1_proj(const float* __restrict__ x,
                                               const float* __restrict__ Wp,
                                               float* __restrict__ h1) {
    __shared__ float sWp[FIN * H];
    __shared__ float sx[8][FIN];
    int tid = threadIdx.x;
    for (int i = tid; i < FIN * H; i += 256) sWp[i] = Wp[i];
    int nb = blockIdx.x * 8;
    int nl = tid >> 5, j = tid & 31;
    int n = nb + nl;
    if (n < NN) sx[nl][j] = x[(size_t)n * FIN + j];
    __syncthreads();
    float acc = 0.f;
#pragma unroll
    for (int k = 0; k < FIN; ++k) acc += sx[nl][k] * sWp[k * H + j];
    if (n < NN) h1[(size_t)n * H + j] = acc;
}

// ---------- K4: h2 = hrelu @ W2p ----------
__global__ __launch_bounds__(320) void k4_proj2(const float* __restrict__ hin,
                                                const float* __restrict__ Wp,
                                                float* __restrict__ h2) {
    __shared__ float sWp[FIN * NC];
    __shared__ float shn[8][FIN];
    int tid = threadIdx.x;
    for (int i = tid; i < FIN * NC; i += 320) sWp[i] = Wp[i];
    int nb = blockIdx.x * 8;
    if (tid < 256) {
        int r = tid >> 5, c = tid & 31;
        shn[r][c] = hin[(size_t)(nb + r) * FIN + c];
    }
    __syncthreads();
    int nl = tid / NC, j = tid % NC;
    int n = nb + nl;
    float acc = 0.f;
#pragma unroll
    for (int k = 0; k < FIN; ++k) acc += shn[nl][k] * sWp[k * NC + j];
    if (n < NN) h2[(size_t)n * NC + j] = acc;
}

// ---------- aggregation: agg[d] = sum CSR w * h[src]; float4 per thread, no atomics ----------
template <int FQ>  // FQ = F/4
__global__ __launch_bounds__(256) void k_agg(const int* __restrict__ offsets,
                                             const int2* __restrict__ evs,
                                             const float* __restrict__ h,
                                             float* __restrict__ agg) {
    int idx = blockIdx.x * 256 + threadIdx.x;
    int n = idx / FQ, q = idx % FQ;
    if (n >= NN) return;
    const float4* h4 = (const float4*)h;
    int s0 = offsets[n], s1 = offsets[n + 1];
    float4 acc = make_float4(0.f, 0.f, 0.f, 0.f);
    for (int e = s0; e < s1; ++e) {
        int2 r = evs[e];
        float w = __int_as_float(r.y);
        float4 hv = h4[(size_t)r.x * FQ + q];
        acc.x += w * hv.x;
        acc.y += w * hv.y;
        acc.z += w * hv.z;
        acc.w += w * hv.w;
    }
    ((float4*)agg)[(size_t)n * FQ + q] = acc;
}

// ---------- K3: GRU layer1 + relu. block = 32 j-lanes x 8 slots, 4 nodes/thread ----------
__global__ __launch_bounds__(256) void k3_gru1(const float* __restrict__ aggh,
                                               const float* __restrict__ h1,
                                               const float* __restrict__ Wc,   // [32][96] k-major
                                               const float* __restrict__ WhT,  // [32][96] k-major
                                               const float* __restrict__ bih,
                                               const float* __restrict__ bhh,
                                               float* __restrict__ out) {
    __shared__ float sA[1024], sH[1024], sWc[3072], sWT[3072];
    int tid = threadIdx.x;
    int nb = blockIdx.x * 32;
    ((float4*)sA)[tid] = ((const float4*)(aggh + (size_t)nb * H))[tid];
    ((float4*)sH)[tid] = ((const float4*)(h1 + (size_t)nb * H))[tid];
    for (int i = tid; i < 768; i += 256) {
        ((float4*)sWc)[i] = ((const float4*)Wc)[i];
        ((float4*)sWT)[i] = ((const float4*)WhT)[i];
    }
    __syncthreads();
    int j = tid & 31, slot = tid >> 5;
    int r0 = slot * 4;
    float ar[4] = {0, 0, 0, 0}, az[4] = {0, 0, 0, 0}, an[4] = {0, 0, 0, 0};
    float hr[4] = {0, 0, 0, 0}, hz[4] = {0, 0, 0, 0}, hn[4] = {0, 0, 0, 0};
#pragma unroll
    for (int kc = 0; kc < 8; ++kc) {
        float4 a4[4], h4[4];
#pragma unroll
        for (int m = 0; m < 4; ++m) {
            a4[m] = *(const float4*)&sA[(r0 + m) * 32 + kc * 4];
            h4[m] = *(const float4*)&sH[(r0 + m) * 32 + kc * 4];
        }
#pragma unroll
        for (int kk = 0; kk < 4; ++kk) {
            int k = kc * 4 + kk;
            float wr = sWc[k * 96 + j], wz = sWc[k * 96 + 32 + j], wn = sWc[k * 96 + 64 + j];
            float ur = sWT[k * 96 + j], uz = sWT[k * 96 + 32 + j], un = sWT[k * 96 + 64 + j];
#pragma unroll
            for (int m = 0; m < 4; ++m) {
                float ak = ((const float*)&a4[m])[kk];
                float hk = ((const float*)&h4[m])[kk];
                ar[m] += wr * ak; az[m] += wz * ak; an[m] += wn * ak;
                hr[m] += ur * hk; hz[m] += uz * hk; hn[m] += un * hk;
            }
        }
    }
    float b_r = bih[j] + bhh[j];
    float b_z = bih[H + j] + bhh[H + j];
    float bin = bih[2 * H + j];
    float bhn = bhh[2 * H + j];
#pragma unroll
    for (int m = 0; m < 4; ++m) {
        float r = sigm_(ar[m] + hr[m] + b_r);
        float z = sigm_(az[m] + hz[m] + b_z);
        float ng = tanh_(an[m] + bin + r * (hn[m] + bhn));
        float hj = sH[(r0 + m) * 32 + j];
        float o = (1.f - z) * ng + z * hj;
        out[(size_t)(nb + r0 + m) * H + j] = fmaxf(o, 0.f);
    }
}

// ---------- K6: GRU layer2 + log_softmax. block = 40 j-lanes x 8 slots, 4 nodes/thread ----------
__global__ __launch_bounds__(320) void k6_gru2(const float* __restrict__ aggh,
                                               const float* __restrict__ h2,
                                               const float* __restrict__ Wc,   // [40][120] k-major
                                               const float* __restrict__ WhT,  // [40][120] k-major
                                               const float* __restrict__ bih,
                                               const float* __restrict__ bhh,
                                               float* __restrict__ out) {
    // smem: sA[1280] | sH[1280] | sWc[4800] | sWT[4800] | sLs[32]; sOut(32x41) overlays sA(+sH head)
    __shared__ float smem[12192];
    float* sA = smem;
    float* sH = smem + 1280;
    float* sWc = smem + 2560;
    float* sWT = smem + 7360;
    float* sLs = smem + 12160;
    int tid = threadIdx.x;
    int nb = blockIdx.x * 32;
    ((float4*)sA)[tid] = ((const float4*)(aggh + (size_t)nb * NC))[tid];
    ((float4*)sH)[tid] = ((const float4*)(h2 + (size_t)nb * NC))[tid];
    for (int i = tid; i < 1200; i += 320) {
        ((float4*)sWc)[i] = ((const float4*)Wc)[i];
        ((float4*)sWT)[i] = ((const float4*)WhT)[i];
    }
    __syncthreads();
    int j = tid % NC, slot = tid / NC;
    int r0 = slot * 4;
    float ar[4] = {0, 0, 0, 0}, az[4] = {0, 0, 0, 0}, an[4] = {0, 0, 0, 0};
    float hr[4] = {0, 0, 0, 0}, hz[4] = {0, 0, 0, 0}, hn[4] = {0, 0, 0, 0};
#pragma unroll
    for (int kc = 0; kc < 10; ++kc) {
        float4 a4[4], h4[4];
#pragma unroll
        for (int m = 0; m < 4; ++m) {
            a4[m] = *(const float4*)&sA[(r0 + m) * 40 + kc * 4];
            h4[m] = *(const float4*)&sH[(r0 + m) * 40 + kc * 4];
        }
#pragma unroll
        for (int kk = 0; kk < 4; ++kk) {
            int k = kc * 4 + kk;
            float wr = sWc[k * 120 + j], wz = sWc[k * 120 + 40 + j], wn = sWc[k * 120 + 80 + j];
            float ur = sWT[k * 120 + j], uz = sWT[k * 120 + 40 + j], un = sWT[k * 120 + 80 + j];
#pragma unroll
            for (int m = 0; m < 4; ++m) {
                float ak = ((const float*)&a4[m])[kk];
                float hk = ((const float*)&h4[m])[kk];
                ar[m] += wr * ak; az[m] += wz * ak; an[m] += wn * ak;
                hr[m] += ur * hk; hz[m] += uz * hk; hn[m] += un * hk;
            }
        }
    }
    float b_r = bih[j] + bhh[j];
    float b_z = bih[NC + j] + bhh[NC + j];
    float bin = bih[2 * NC + j];
    float bhn = bhh[2 * NC + j];
    float v[4];
#pragma unroll
    for (int m = 0; m < 4; ++m) {
        float r = sigm_(ar[m] + hr[m] + b_r);
        float z = sigm_(az[m] + hz[m] + b_z);
        float ng = tanh_(an[m] + bin + r * (hn[m] + bhn));
        float hj = sH[(r0 + m) * 40 + j];
        v[m] = (1.f - z) * ng + z * hj;
    }
    __syncthreads();  // all reads of sA/sH done before overlay
    float* sOut = smem;  // stride 41 -> conflict-free column reads
#pragma unroll
    for (int m = 0; m < 4; ++m) sOut[(r0 + m) * 41 + j] = v[m];
    __syncthreads();
    if (tid < 32) {
        const float* row = sOut + tid * 41;
        float mx = row[0];
#pragma unroll
        for (int t = 1; t < NC; ++t) mx = fmaxf(mx, row[t]);
        float s = 0.f;
#pragma unroll
        for (int t = 0; t < NC; ++t) s += __expf(row[t] - mx);
        sLs[tid] = mx + __logf(s);
    }
    __syncthreads();
#pragma unroll
    for (int m = 0; m < 4; ++m)
        out[(size_t)(nb + r0 + m) * NC + j] = v[m] - sLs[r0 + m];
}

extern "C" void kernel_launch(void* const* d_in, const int* in_sizes, int n_in,
                              void* d_out, int out_size, void* d_ws, size_t ws_size,
                              hipStream_t stream) {
    const float* x = (const float*)d_in[0];
    const int* ei = (const int*)d_in[1];
    const float* ew = (const float*)d_in[2];
    const float* W1p = (const float*)d_in[3];
    const float* W1m = (const float*)d_in[4];
    const float* g1wih = (const float*)d_in[5];
    const float* g1whh = (const float*)d_in[6];
    const float* g1bih = (const float*)d_in[7];
    const float* g1bhh = (const float*)d_in[8];
    const float* W2p = (const float*)d_in[9];
    const float* W2m = (const float*)d_in[10];
    const float* g2wih = (const float*)d_in[11];
    const float* g2whh = (const float*)d_in[12];
    const float* g2bih = (const float*)d_in[13];
    const float* g2bhh = (const float*)d_in[14];
    float* ws = (float*)d_ws;

    // workspace layout (floats) — lifetime-overlapped, ~62 MB (same proven footprint):
    float* A = ws + 0;               // h1 [N,32] then h2 [N,40]
    float* B = ws + 4000000;         // aggh1 [N,32] then aggh2 [N,40]
    float* C = ws + 8000000;         // hrelu [N,32] (live k3..k4)
    int* rank = (int*)(ws + 8000000);      // 2M ints, live k_hist..k_fill (before C is live)
    int2* evs = (int2*)(ws + 11200000);    // 2M int2 (16 MB)
    int* offs = (int*)(ws + 15200000);     // 100001
    int* cnts = (int*)(ws + 15300004);     // 100000 (dead after scan1)
    int* bsum = (int*)(ws + 15500004);     // 128
    float* Wc1 = ws + 15500136;            // 3072
    float* Wc2 = ws + 15503208;            // 4800
    float* WhT1 = (float*)(ws + 15300004); // 3072, overlays dead cnts
    float* WhT2 = (float*)(ws + 15400004); // 4800
    float* out = (float*)d_out;

    // ---- CSR build (shared by both layers) ----
    hipMemsetAsync(cnts, 0, (size_t)NN * sizeof(int), stream);
    k_hist<<<(NE + 255) / 256, 256, 0, stream>>>(ei, cnts, rank);
    k_scan1<<<NB_SCAN, 256, 0, stream>>>(cnts, offs, bsum);
    k_scan2<<<1, 128, 0, stream>>>(bsum);
    k_scan3<<<(NN + 255) / 256, 256, 0, stream>>>(bsum, offs);
    k_fill<<<(NE + 255) / 256, 256, 0, stream>>>(ei, ew, offs, rank, evs);
    k_wc<<<(2 * (H * 3 * H + NC * 3 * NC) + 255) / 256, 256, 0, stream>>>(
        W1m, g1wih, W2m, g2wih, g1whh, g2whh, Wc1, Wc2, WhT1, WhT2);

    // ---- layer 1 ----
    k1_proj<<<(NN + 7) / 8, 256, 0, stream>>>(x, W1p, A);
    k_agg<8><<<(NN * 8 + 255) / 256, 256, 0, stream>>>(offs, evs, A, B);
    k3_gru1<<<NN / 32, 256, 0, stream>>>(B, A, Wc1, WhT1, g1bih, g1bhh, C);

    // ---- layer 2 ----
    k4_proj2<<<(NN + 7) / 8, 320, 0, stream>>>(C, W2p, A);
    k_agg<10><<<(NN * 10 + 255) / 256, 256, 0, stream>>>(offs, evs, A, B);
    k6_gru2<<<NN / 32, 320, 0, stream>>>(B, A, Wc2, WhT2, g2bih, g2bhh, out);
}

// Round 5
// 403.912 us; speedup vs baseline: 19.5748x; 1.1518x over previous
//
#include <hip/hip_runtime.h>
#include <math.h>

#define NN 100000
#define NE 2000000
#define FIN 32
#define H 32
#define NC 40

#define NBK 196      // coarse buckets: dst>>9 (512 nodes each)
#define BSH 9
#define CAP 11264    // per-bucket capacity: mean 10240 + ~10 sigma
#define EPT 16
#define EPB (256 * EPT)  // 4096 edges per block

__device__ __forceinline__ float sigm_(float x) {
    return 1.0f / (1.0f + __expf(-x));
}
__device__ __forceinline__ float tanh_(float x) {
    x = fminf(fmaxf(x, -20.0f), 20.0f);
    float e = __expf(2.0f * x);
    return (e - 1.0f) / (e + 1.0f);
}

// ---------- phase A: coarse-bucket scatter; per-edge atomics are LDS-only ----------
__global__ __launch_bounds__(256) void kA_bucket(const int* __restrict__ ei,
                                                 const float* __restrict__ ew,
                                                 int* __restrict__ gcur,
                                                 int2* __restrict__ rec) {
    __shared__ int cnt[NBK], base[NBK];
    int tid = threadIdx.x;
    for (int i = tid; i < NBK; i += 256) cnt[i] = 0;
    __syncthreads();
    int e0 = blockIdx.x * EPB;
    for (int i = 0; i < EPT; ++i) {
        int e = e0 + i * 256 + tid;
        if (e < NE) atomicAdd(&cnt[ei[NE + e] >> BSH], 1);
    }
    __syncthreads();
    for (int i = tid; i < NBK; i += 256) {
        base[i] = atomicAdd(&gcur[i], cnt[i]);  // one global atomic per (block,bucket)
        cnt[i] = 0;
    }
    __syncthreads();
    for (int i = 0; i < EPT; ++i) {
        int e = e0 + i * 256 + tid;
        if (e < NE) {
            int d = ei[NE + e], s = ei[e];
            int b = d >> BSH;
            int r = atomicAdd(&cnt[b], 1);
            int pos = base[b] + r;
            if (pos < CAP)  // statistically impossible overflow guard
                rec[(size_t)b * CAP + pos] =
                    make_int2(s | ((d & 511) << 17), __float_as_int(ew[e]));
        }
    }
}

// ---------- phase B: per-bucket local counting sort (LDS hist + scan + rank) ----------
__global__ __launch_bounds__(256) void kB_sort(const int* __restrict__ gcur,
                                               const int2* __restrict__ rec,
                                               int2* __restrict__ evs,
                                               int* __restrict__ ofs,
                                               int* __restrict__ ocn) {
    __shared__ int hist[512], lofs[512], ssc[256];
    int tid = threadIdx.x, b = blockIdx.x;
    int nb0 = b << BSH;
    int nnodes = min(512, NN - nb0);
    int cntb = min(gcur[b], CAP);
    hist[tid] = 0;
    hist[tid + 256] = 0;
    __syncthreads();
    const int2* rb = rec + (size_t)b * CAP;
    for (int i = tid; i < cntb; i += 256)
        atomicAdd(&hist[(rb[i].x >> 17) & 511], 1);
    __syncthreads();
    int ps = hist[2 * tid] + hist[2 * tid + 1];
    ssc[tid] = ps;
    __syncthreads();
    for (int off = 1; off < 256; off <<= 1) {
        int v = (tid >= off) ? ssc[tid - off] : 0;
        __syncthreads();
        ssc[tid] += v;
        __syncthreads();
    }
    int ex = ssc[tid] - ps;  // exclusive over pairs
    lofs[2 * tid] = ex;
    lofs[2 * tid + 1] = ex + hist[2 * tid];
    __syncthreads();
    for (int l = tid; l < nnodes; l += 256) {  // per-node CSR meta (coalesced)
        ofs[nb0 + l] = b * CAP + lofs[l];
        ocn[nb0 + l] = hist[l];
    }
    hist[tid] = 0;  // same thread zeroes exactly the bins it read above
    hist[tid + 256] = 0;
    __syncthreads();
    int2* eb = evs + (size_t)b * CAP;
    for (int i = tid; i < cntb; i += 256) {
        int2 r = rb[i];
        int dl = (r.x >> 17) & 511;
        int rk = atomicAdd(&hist[dl], 1);
        eb[lofs[dl] + rk] = make_int2(r.x & 0x1FFFF, r.y);
    }
}

// ---------- precompute Wc = Wm @ wih^T (k-major) and WhhT (k-major transpose of whh) ----------
__global__ __launch_bounds__(256) void k_wc(const float* __restrict__ W1m,
                                            const float* __restrict__ wih1,
                                            const float* __restrict__ W2m,
                                            const float* __restrict__ wih2,
                                            const float* __restrict__ whh1,
                                            const float* __restrict__ whh2,
                                            float* __restrict__ Wc1,
                                            float* __restrict__ Wc2,
                                            float* __restrict__ WhT1,
                                            float* __restrict__ WhT2) {
    int i = blockIdx.x * 256 + threadIdx.x;
    if (i < H * 3 * H) {  // Wc1[k*96 + c]
        int k = i / (3 * H), g = i % (3 * H);
        float acc = 0.f;
#pragma unroll
        for (int t = 0; t < H; ++t) acc += W1m[k * H + t] * wih1[g * H + t];
        Wc1[i] = acc;
    } else if (i < H * 3 * H + NC * 3 * NC) {  // Wc2[k*120 + c]
        int j = i - H * 3 * H;
        int k = j / (3 * NC), g = j % (3 * NC);
        float acc = 0.f;
#pragma unroll
        for (int t = 0; t < NC; ++t) acc += W2m[k * NC + t] * wih2[g * NC + t];
        Wc2[j] = acc;
    } else if (i < H * 3 * H + NC * 3 * NC + H * 3 * H) {  // WhT1[k*96 + c] = whh1[c*32 + k]
        int t = i - (H * 3 * H + NC * 3 * NC);
        int k = t / (3 * H), c = t % (3 * H);
        WhT1[t] = whh1[c * H + k];
    } else if (i < H * 3 * H + NC * 3 * NC + H * 3 * H + NC * 3 * NC) {
        int t = i - (H * 3 * H + NC * 3 * NC + H * 3 * H);
        int k = t / (3 * NC), c = t % (3 * NC);
        WhT2[t] = whh2[c * NC + k];
    }
}

// ---------- K1: h1 = x @ W1p ----------
__global__ __launch_bounds__(256) void k1_proj(const float* __restrict__ x,
                                               const float* __restrict__ Wp,
                                               float* __restrict__ h1) {
    __shared__ float sWp[FIN * H];
    __shared__ float sx[8][FIN];
    int tid = threadIdx.x;
    for (int i = tid; i < FIN * H; i += 256) sWp[i] = Wp[i];
    int nb = blockIdx.x * 8;
    int nl = tid >> 5, j = tid & 31;
    int n = nb + nl;
    if (n < NN) sx[nl][j] = x[(size_t)n * FIN + j];
    __syncthreads();
    float acc = 0.f;
#pragma unroll
    for (int k = 0; k < FIN; ++k) acc += sx[nl][k] * sWp[k * H + j];
    if (n < NN) h1[(size_t)n * H + j] = acc;
}

// ---------- K4: h2 = hrelu @ W2p ----------
__global__ __launch_bounds__(320) void k4_proj2(const float* __restrict__ hin,
                                                const float* __restrict__ Wp,
                                                float* __restrict__ h2) {
    __shared__ float sWp[FIN * NC];
    __shared__ float shn[8][FIN];
    int tid = threadIdx.x;
    for (int i = tid; i < FIN * NC; i += 320) sWp[i] = Wp[i];
    int nb = blockIdx.x * 8;
    if (tid < 256) {
        int r = tid >> 5, c = tid & 31;
        shn[r][c] = hin[(size_t)(nb + r) * FIN + c];
    }
    __syncthreads();
    int nl = tid / NC, j = tid % NC;
    int n = nb + nl;
    float acc = 0.f;
#pragma unroll
    for (int k = 0; k < FIN; ++k) acc += shn[nl][k] * sWp[k * NC + j];
    if (n < NN) h2[(size_t)n * NC + j] = acc;
}

// ---------- aggregation: agg[d] = sum CSR w * h[src]; float4 per thread, no atomics ----------
template <int FQ>  // FQ = F/4
__global__ __launch_bounds__(256) void k_agg(const int* __restrict__ ofs,
                                             const int* __restrict__ ocn,
                                             const int2* __restrict__ evs,
                                             const float* __restrict__ h,
                                             float* __restrict__ agg) {
    int idx = blockIdx.x * 256 + threadIdx.x;
    int n = idx / FQ, q = idx % FQ;
    if (n >= NN) return;
    const float4* h4 = (const float4*)h;
    int s0 = ofs[n], c = ocn[n];
    float4 acc = make_float4(0.f, 0.f, 0.f, 0.f);
    for (int e = s0; e < s0 + c; ++e) {
        int2 r = evs[e];
        float w = __int_as_float(r.y);
        float4 hv = h4[(size_t)r.x * FQ + q];
        acc.x += w * hv.x;
        acc.y += w * hv.y;
        acc.z += w * hv.z;
        acc.w += w * hv.w;
    }
    ((float4*)agg)[(size_t)n * FQ + q] = acc;
}

// ---------- K3: GRU layer1 + relu. block = 32 j-lanes x 8 slots, 4 nodes/thread ----------
__global__ __launch_bounds__(256) void k3_gru1(const float* __restrict__ aggh,
                                               const float* __restrict__ h1,
                                               const float* __restrict__ Wc,   // [32][96] k-major
                                               const float* __restrict__ WhT,  // [32][96] k-major
                                               const float* __restrict__ bih,
                                               const float* __restrict__ bhh,
                                               float* __restrict__ out) {
    __shared__ float sA[1024], sH[1024], sWc[3072], sWT[3072];
    int tid = threadIdx.x;
    int nb = blockIdx.x * 32;
    ((float4*)sA)[tid] = ((const float4*)(aggh + (size_t)nb * H))[tid];
    ((float4*)sH)[tid] = ((const float4*)(h1 + (size_t)nb * H))[tid];
    for (int i = tid; i < 768; i += 256) {
        ((float4*)sWc)[i] = ((const float4*)Wc)[i];
        ((float4*)sWT)[i] = ((const float4*)WhT)[i];
    }
    __syncthreads();
    int j = tid & 31, slot = tid >> 5;
    int r0 = slot * 4;
    float ar[4] = {0, 0, 0, 0}, az[4] = {0, 0, 0, 0}, an[4] = {0, 0, 0, 0};
    float hr[4] = {0, 0, 0, 0}, hz[4] = {0, 0, 0, 0}, hn[4] = {0, 0, 0, 0};
#pragma unroll
    for (int kc = 0; kc < 8; ++kc) {
        float4 a4[4], h4[4];
#pragma unroll
        for (int m = 0; m < 4; ++m) {
            a4[m] = *(const float4*)&sA[(r0 + m) * 32 + kc * 4];
            h4[m] = *(const float4*)&sH[(r0 + m) * 32 + kc * 4];
        }
#pragma unroll
        for (int kk = 0; kk < 4; ++kk) {
            int k = kc * 4 + kk;
            float wr = sWc[k * 96 + j], wz = sWc[k * 96 + 32 + j], wn = sWc[k * 96 + 64 + j];
            float ur = sWT[k * 96 + j], uz = sWT[k * 96 + 32 + j], un = sWT[k * 96 + 64 + j];
#pragma unroll
            for (int m = 0; m < 4; ++m) {
                float ak = ((const float*)&a4[m])[kk];
                float hk = ((const float*)&h4[m])[kk];
                ar[m] += wr * ak; az[m] += wz * ak; an[m] += wn * ak;
                hr[m] += ur * hk; hz[m] += uz * hk; hn[m] += un * hk;
            }
        }
    }
    float b_r = bih[j] + bhh[j];
    float b_z = bih[H + j] + bhh[H + j];
    float bin = bih[2 * H + j];
    float bhn = bhh[2 * H + j];
#pragma unroll
    for (int m = 0; m < 4; ++m) {
        float r = sigm_(ar[m] + hr[m] + b_r);
        float z = sigm_(az[m] + hz[m] + b_z);
        float ng = tanh_(an[m] + bin + r * (hn[m] + bhn));
        float hj = sH[(r0 + m) * 32 + j];
        float o = (1.f - z) * ng + z * hj;
        out[(size_t)(nb + r0 + m) * H + j] = fmaxf(o, 0.f);
    }
}

// ---------- K6: GRU layer2 + log_softmax. block = 40 j-lanes x 8 slots, 4 nodes/thread ----------
__global__ __launch_bounds__(320) void k6_gru2(const float* __restrict__ aggh,
                                               const float* __restrict__ h2,
                                               const float* __restrict__ Wc,   // [40][120] k-major
                                               const float* __restrict__ WhT,  // [40][120] k-major
                                               const float* __restrict__ bih,
                                               const float* __restrict__ bhh,
                                               float* __restrict__ out) {
    // smem: sA[1280] | sH[1280] | sWc[4800] | sWT[4800] | sLs[32]; sOut(32x41) overlays sA(+sH head)
    __shared__ float smem[12192];
    float* sA = smem;
    float* sH = smem + 1280;
    float* sWc = smem + 2560;
    float* sWT = smem + 7360;
    float* sLs = smem + 12160;
    int tid = threadIdx.x;
    int nb = blockIdx.x * 32;
    ((float4*)sA)[tid] = ((const float4*)(aggh + (size_t)nb * NC))[tid];
    ((float4*)sH)[tid] = ((const float4*)(h2 + (size_t)nb * NC))[tid];
    for (int i = tid; i < 1200; i += 320) {
        ((float4*)sWc)[i] = ((const float4*)Wc)[i];
        ((float4*)sWT)[i] = ((const float4*)WhT)[i];
    }
    __syncthreads();
    int j = tid % NC, slot = tid / NC;
    int r0 = slot * 4;
    float ar[4] = {0, 0, 0, 0}, az[4] = {0, 0, 0, 0}, an[4] = {0, 0, 0, 0};
    float hr[4] = {0, 0, 0, 0}, hz[4] = {0, 0, 0, 0}, hn[4] = {0, 0, 0, 0};
#pragma unroll
    for (int kc = 0; kc < 10; ++kc) {
        float4 a4[4], h4[4];
#pragma unroll
        for (int m = 0; m < 4; ++m) {
            a4[m] = *(const float4*)&sA[(r0 + m) * 40 + kc * 4];
            h4[m] = *(const float4*)&sH[(r0 + m) * 40 + kc * 4];
        }
#pragma unroll
        for (int kk = 0; kk < 4; ++kk) {
            int k = kc * 4 + kk;
            float wr = sWc[k * 120 + j], wz = sWc[k * 120 + 40 + j], wn = sWc[k * 120 + 80 + j];
            float ur = sWT[k * 120 + j], uz = sWT[k * 120 + 40 + j], un = sWT[k * 120 + 80 + j];
#pragma unroll
            for (int m = 0; m < 4; ++m) {
                float ak = ((const float*)&a4[m])[kk];
                float hk = ((const float*)&h4[m])[kk];
                ar[m] += wr * ak; az[m] += wz * ak; an[m] += wn * ak;
                hr[m] += ur * hk; hz[m] += uz * hk; hn[m] += un * hk;
            }
        }
    }
    float b_r = bih[j] + bhh[j];
    float b_z = bih[NC + j] + bhh[NC + j];
    float bin = bih[2 * NC + j];
    float bhn = bhh[2 * NC + j];
    float v[4];
#pragma unroll
    for (int m = 0; m < 4; ++m) {
        float r = sigm_(ar[m] + hr[m] + b_r);
        float z = sigm_(az[m] + hz[m] + b_z);
        float ng = tanh_(an[m] + bin + r * (hn[m] + bhn));
        float hj = sH[(r0 + m) * 40 + j];
        v[m] = (1.f - z) * ng + z * hj;
    }
    __syncthreads();  // all reads of sA/sH done before overlay
    float* sOut = smem;  // stride 41 -> conflict-free column reads
#pragma unroll
    for (int m = 0; m < 4; ++m) sOut[(r0 + m) * 41 + j] = v[m];
    __syncthreads();
    if (tid < 32) {
        const float* row = sOut + tid * 41;
        float mx = row[0];
#pragma unroll
        for (int t = 1; t < NC; ++t) mx = fmaxf(mx, row[t]);
        float s = 0.f;
#pragma unroll
        for (int t = 0; t < NC; ++t) s += __expf(row[t] - mx);
        sLs[tid] = mx + __logf(s);
    }
    __syncthreads();
#pragma unroll
    for (int m = 0; m < 4; ++m)
        out[(size_t)(nb + r0 + m) * NC + j] = v[m] - sLs[r0 + m];
}

extern "C" void kernel_launch(void* const* d_in, const int* in_sizes, int n_in,
                              void* d_out, int out_size, void* d_ws, size_t ws_size,
                              hipStream_t stream) {
    const float* x = (const float*)d_in[0];
    const int* ei = (const int*)d_in[1];
    const float* ew = (const float*)d_in[2];
    const float* W1p = (const float*)d_in[3];
    const float* W1m = (const float*)d_in[4];
    const float* g1wih = (const float*)d_in[5];
    const float* g1whh = (const float*)d_in[6];
    const float* g1bih = (const float*)d_in[7];
    const float* g1bhh = (const float*)d_in[8];
    const float* W2p = (const float*)d_in[9];
    const float* W2m = (const float*)d_in[10];
    const float* g2wih = (const float*)d_in[11];
    const float* g2whh = (const float*)d_in[12];
    const float* g2bih = (const float*)d_in[13];
    const float* g2bhh = (const float*)d_in[14];
    float* ws = (float*)d_ws;

    // workspace layout (float indices), ~50 MB total:
    float* A = ws + 0;                       // h1 [N,32] then h2 [N,40]
    float* B = ws + 4000000;                 // aggh1 then aggh2
    int2* rec = (int2*)ws;                   // 196*CAP records, live only during CSR build (overlays A+B)
    int2* evs = (int2*)(ws + 8000000);       // 196*CAP sorted records (17.7 MB)
    int* ofs = (int*)(ws + 12415488);        // 100000 per-node start (padded CSR)
    int* ocn = (int*)(ws + 12515488);        // 100000 per-node count
    int* gcur = (int*)(ws + 12615488);       // 196 bucket cursors
    float* Wc1 = ws + 12615684;              // 3072
    float* Wc2 = Wc1 + 3072;                 // 4800
    float* WhT1 = Wc2 + 4800;                // 3072
    float* WhT2 = WhT1 + 3072;               // 4800
    float* hrelu = (float*)d_out;            // [N,32] overlays d_out; k6 overwrites later
    float* out = (float*)d_out;

    // ---- CSR build (shared by both layers) ----
    hipMemsetAsync(gcur, 0, NBK * sizeof(int), stream);
    kA_bucket<<<(NE + EPB - 1) / EPB, 256, 0, stream>>>(ei, ew, gcur, rec);
    kB_sort<<<NBK, 256, 0, stream>>>(gcur, rec, evs, ofs, ocn);
    k_wc<<<(2 * (H * 3 * H + NC * 3 * NC) + 255) / 256, 256, 0, stream>>>(
        W1m, g1wih, W2m, g2wih, g1whh, g2whh, Wc1, Wc2, WhT1, WhT2);

    // ---- layer 1 ----
    k1_proj<<<(NN + 7) / 8, 256, 0, stream>>>(x, W1p, A);
    k_agg<8><<<(NN * 8 + 255) / 256, 256, 0, stream>>>(ofs, ocn, evs, A, B);
    k3_gru1<<<NN / 32, 256, 0, stream>>>(B, A, Wc1, WhT1, g1bih, g1bhh, hrelu);

    // ---- layer 2 ----
    k4_proj2<<<(NN + 7) / 8, 320, 0, stream>>>(hrelu, W2p, A);
    k_agg<10><<<(NN * 10 + 255) / 256, 256, 0, stream>>>(ofs, ocn, evs, A, B);
    k6_gru2<<<NN / 32, 320, 0, stream>>>(B, A, Wc2, WhT2, g2bih, g2bhh, out);
}

// Round 6
// 388.110 us; speedup vs baseline: 20.3719x; 1.0407x over previous
//
#include <hip/hip_runtime.h>
#include <math.h>

#define NN 100000
#define NE 2000000
#define FIN 32
#define H 32
#define NC 40

#define NBK 196      // coarse buckets: dst>>9 (512 nodes each)
#define BSH 9
#define CAP 11264    // per-bucket capacity: mean 10240 + ~10 sigma
#define EPT 16
#define EPB (256 * EPT)  // 4096 edges per block

typedef _Float16 half_t;
typedef __attribute__((ext_vector_type(8))) _Float16 half8;

__device__ __forceinline__ float sigm_(float x) {
    return 1.0f / (1.0f + __expf(-x));
}
__device__ __forceinline__ float tanh_(float x) {
    x = fminf(fmaxf(x, -20.0f), 20.0f);
    float e = __expf(2.0f * x);
    return (e - 1.0f) / (e + 1.0f);
}

// ---------- phase A: coarse-bucket scatter; per-edge atomics are LDS-only ----------
__global__ __launch_bounds__(256) void kA_bucket(const int* __restrict__ ei,
                                                 const float* __restrict__ ew,
                                                 int* __restrict__ gcur,
                                                 int2* __restrict__ rec) {
    __shared__ int cnt[NBK], base[NBK];
    int tid = threadIdx.x;
    for (int i = tid; i < NBK; i += 256) cnt[i] = 0;
    __syncthreads();
    int e0 = blockIdx.x * EPB;
    for (int i = 0; i < EPT; ++i) {
        int e = e0 + i * 256 + tid;
        if (e < NE) atomicAdd(&cnt[ei[NE + e] >> BSH], 1);
    }
    __syncthreads();
    for (int i = tid; i < NBK; i += 256) {
        base[i] = atomicAdd(&gcur[i], cnt[i]);  // one global atomic per (block,bucket)
        cnt[i] = 0;
    }
    __syncthreads();
    for (int i = 0; i < EPT; ++i) {
        int e = e0 + i * 256 + tid;
        if (e < NE) {
            int d = ei[NE + e], s = ei[e];
            int b = d >> BSH;
            int r = atomicAdd(&cnt[b], 1);
            int pos = base[b] + r;
            if (pos < CAP)  // statistically impossible overflow guard
                rec[(size_t)b * CAP + pos] =
                    make_int2(s | ((d & 511) << 17), __float_as_int(ew[e]));
        }
    }
}

// ---------- phase B: per-bucket local counting sort (LDS hist + scan + rank) ----------
__global__ __launch_bounds__(256) void kB_sort(const int* __restrict__ gcur,
                                               const int2* __restrict__ rec,
                                               int2* __restrict__ evs,
                                               int* __restrict__ ofs,
                                               int* __restrict__ ocn) {
    __shared__ int hist[512], lofs[512], ssc[256];
    int tid = threadIdx.x, b = blockIdx.x;
    int nb0 = b << BSH;
    int nnodes = min(512, NN - nb0);
    int cntb = min(gcur[b], CAP);
    hist[tid] = 0;
    hist[tid + 256] = 0;
    __syncthreads();
    const int2* rb = rec + (size_t)b * CAP;
    for (int i = tid; i < cntb; i += 256)
        atomicAdd(&hist[(rb[i].x >> 17) & 511], 1);
    __syncthreads();
    int ps = hist[2 * tid] + hist[2 * tid + 1];
    ssc[tid] = ps;
    __syncthreads();
    for (int off = 1; off < 256; off <<= 1) {
        int v = (tid >= off) ? ssc[tid - off] : 0;
        __syncthreads();
        ssc[tid] += v;
        __syncthreads();
    }
    int ex = ssc[tid] - ps;  // exclusive over pairs
    lofs[2 * tid] = ex;
    lofs[2 * tid + 1] = ex + hist[2 * tid];
    __syncthreads();
    for (int l = tid; l < nnodes; l += 256) {  // per-node CSR meta (coalesced)
        ofs[nb0 + l] = b * CAP + lofs[l];
        ocn[nb0 + l] = hist[l];
    }
    hist[tid] = 0;  // same thread zeroes exactly the bins it read above
    hist[tid + 256] = 0;
    __syncthreads();
    int2* eb = evs + (size_t)b * CAP;
    for (int i = tid; i < cntb; i += 256) {
        int2 r = rb[i];
        int dl = (r.x >> 17) & 511;
        int rk = atomicAdd(&hist[dl], 1);
        eb[lofs[dl] + rk] = make_int2(r.x & 0x1FFFF, r.y);
    }
}

// ---------- precompute folded weight matrices ----------
// Wc1 [32][96]  = W1m @ wih1^T              (k-major)
// Wc2c [32][120]= W2p @ W2m @ wih2^T        (k-major, W2p folded in)
// WhT1 [32][96] = whh1^T ; WhT2 [40][120] = whh2^T
__global__ __launch_bounds__(256) void k_wc(const float* __restrict__ W1m,
                                            const float* __restrict__ wih1,
                                            const float* __restrict__ W2p,
                                            const float* __restrict__ W2m,
                                            const float* __restrict__ wih2,
                                            const float* __restrict__ whh1,
                                            const float* __restrict__ whh2,
                                            float* __restrict__ Wc1,
                                            float* __restrict__ Wc2c,
                                            float* __restrict__ WhT1,
                                            float* __restrict__ WhT2) {
    int i = blockIdx.x * 256 + threadIdx.x;
    const int N1 = H * 3 * H;            // 3072
    const int N2 = FIN * 3 * NC;         // 3840
    const int N3 = H * 3 * H;            // 3072
    const int N4 = NC * 3 * NC;          // 4800
    if (i < N1) {  // Wc1[k*96 + c]
        int k = i / (3 * H), g = i % (3 * H);
        float acc = 0.f;
#pragma unroll
        for (int t = 0; t < H; ++t) acc += W1m[k * H + t] * wih1[g * H + t];
        Wc1[i] = acc;
    } else if (i < N1 + N2) {  // Wc2c[k*120 + c] = sum_u W2p[k,u] * sum_t W2m[u,t]*wih2[c,t]
        int j = i - N1;
        int k = j / (3 * NC), c = j % (3 * NC);
        float acc = 0.f;
        for (int u = 0; u < NC; ++u) {
            float s2 = 0.f;
#pragma unroll
            for (int t = 0; t < NC; ++t) s2 += W2m[u * NC + t] * wih2[c * NC + t];
            acc += W2p[k * NC + u] * s2;
        }
        Wc2c[j] = acc;
    } else if (i < N1 + N2 + N3) {  // WhT1[k*96 + c] = whh1[c*32 + k]
        int t = i - (N1 + N2);
        int k = t / (3 * H), c = t % (3 * H);
        WhT1[t] = whh1[c * H + k];
    } else if (i < N1 + N2 + N3 + N4) {
        int t = i - (N1 + N2 + N3);
        int k = t / (3 * NC), c = t % (3 * NC);
        WhT2[t] = whh2[c * NC + k];
    }
}

// ---------- K1: h1 = x @ W1p (fp32 + fp16 gather copy) ----------
__global__ __launch_bounds__(256) void k1_proj(const float* __restrict__ x,
                                               const float* __restrict__ Wp,
                                               float* __restrict__ h1,
                                               half_t* __restrict__ h1h) {
    __shared__ float sWp[FIN * H];
    __shared__ float sx[8][FIN];
    int tid = threadIdx.x;
    for (int i = tid; i < FIN * H; i += 256) sWp[i] = Wp[i];
    int nb = blockIdx.x * 8;
    int nl = tid >> 5, j = tid & 31;
    int n = nb + nl;
    if (n < NN) sx[nl][j] = x[(size_t)n * FIN + j];
    __syncthreads();
    float acc = 0.f;
#pragma unroll
    for (int k = 0; k < FIN; ++k) acc += sx[nl][k] * sWp[k * H + j];
    if (n < NN) {
        h1[(size_t)n * H + j] = acc;
        h1h[(size_t)n * H + j] = (half_t)acc;
    }
}

// ---------- K4: h2 = hrelu @ W2p (fp32, dense consumer only) ----------
__global__ __launch_bounds__(320) void k4_proj2(const float* __restrict__ hin,
                                                const float* __restrict__ Wp,
                                                float* __restrict__ h2) {
    __shared__ float sWp[FIN * NC];
    __shared__ float shn[8][FIN];
    int tid = threadIdx.x;
    for (int i = tid; i < FIN * NC; i += 320) sWp[i] = Wp[i];
    int nb = blockIdx.x * 8;
    if (tid < 256) {
        int r = tid >> 5, c = tid & 31;
        shn[r][c] = hin[(size_t)(nb + r) * FIN + c];
    }
    __syncthreads();
    int nl = tid / NC, j = tid % NC;
    int n = nb + nl;
    float acc = 0.f;
#pragma unroll
    for (int k = 0; k < FIN; ++k) acc += shn[nl][k] * sWp[k * NC + j];
    if (n < NN) h2[(size_t)n * NC + j] = acc;
}

// ---------- aggregation: agg[d] = sum CSR w * h[src]; fp16 table, fp32 accum ----------
// 4 threads per node, each gathers 8 halves (16 B) per edge.
__global__ __launch_bounds__(256) void k_aggh(const int* __restrict__ ofs,
                                              const int* __restrict__ ocn,
                                              const int2* __restrict__ evs,
                                              const half8* __restrict__ h8,
                                              float* __restrict__ agg) {
    int idx = blockIdx.x * 256 + threadIdx.x;
    int n = idx >> 2, q = idx & 3;
    if (n >= NN) return;
    int s0 = ofs[n], c = ocn[n];
    float acc[8] = {0.f, 0.f, 0.f, 0.f, 0.f, 0.f, 0.f, 0.f};
    for (int e = s0; e < s0 + c; ++e) {
        int2 r = evs[e];
        float w = __int_as_float(r.y);
        half8 hv = h8[(size_t)r.x * 4 + q];
#pragma unroll
        for (int t = 0; t < 8; ++t) acc[t] += w * (float)hv[t];
    }
    float4* o = (float4*)(agg + (size_t)n * 32 + q * 8);
    o[0] = make_float4(acc[0], acc[1], acc[2], acc[3]);
    o[1] = make_float4(acc[4], acc[5], acc[6], acc[7]);
}

// ---------- K3: GRU layer1 + relu. block = 32 j-lanes x 8 slots, 4 nodes/thread ----------
__global__ __launch_bounds__(256) void k3_gru1(const float* __restrict__ aggh,
                                               const float* __restrict__ h1,
                                               const float* __restrict__ Wc,   // [32][96] k-major
                                               const float* __restrict__ WhT,  // [32][96] k-major
                                               const float* __restrict__ bih,
                                               const float* __restrict__ bhh,
                                               float* __restrict__ out,
                                               half_t* __restrict__ outh) {
    __shared__ float sA[1024], sH[1024], sWc[3072], sWT[3072];
    int tid = threadIdx.x;
    int nb = blockIdx.x * 32;
    ((float4*)sA)[tid] = ((const float4*)(aggh + (size_t)nb * H))[tid];
    ((float4*)sH)[tid] = ((const float4*)(h1 + (size_t)nb * H))[tid];
    for (int i = tid; i < 768; i += 256) {
        ((float4*)sWc)[i] = ((const float4*)Wc)[i];
        ((float4*)sWT)[i] = ((const float4*)WhT)[i];
    }
    __syncthreads();
    int j = tid & 31, slot = tid >> 5;
    int r0 = slot * 4;
    float ar[4] = {0, 0, 0, 0}, az[4] = {0, 0, 0, 0}, an[4] = {0, 0, 0, 0};
    float hr[4] = {0, 0, 0, 0}, hz[4] = {0, 0, 0, 0}, hn[4] = {0, 0, 0, 0};
#pragma unroll
    for (int kc = 0; kc < 8; ++kc) {
        float4 a4[4], h4[4];
#pragma unroll
        for (int m = 0; m < 4; ++m) {
            a4[m] = *(const float4*)&sA[(r0 + m) * 32 + kc * 4];
            h4[m] = *(const float4*)&sH[(r0 + m) * 32 + kc * 4];
        }
#pragma unroll
        for (int kk = 0; kk < 4; ++kk) {
            int k = kc * 4 + kk;
            float wr = sWc[k * 96 + j], wz = sWc[k * 96 + 32 + j], wn = sWc[k * 96 + 64 + j];
            float ur = sWT[k * 96 + j], uz = sWT[k * 96 + 32 + j], un = sWT[k * 96 + 64 + j];
#pragma unroll
            for (int m = 0; m < 4; ++m) {
                float ak = ((const float*)&a4[m])[kk];
                float hk = ((const float*)&h4[m])[kk];
                ar[m] += wr * ak; az[m] += wz * ak; an[m] += wn * ak;
                hr[m] += ur * hk; hz[m] += uz * hk; hn[m] += un * hk;
            }
        }
    }
    float b_r = bih[j] + bhh[j];
    float b_z = bih[H + j] + bhh[H + j];
    float bin = bih[2 * H + j];
    float bhn = bhh[2 * H + j];
#pragma unroll
    for (int m = 0; m < 4; ++m) {
        float r = sigm_(ar[m] + hr[m] + b_r);
        float z = sigm_(az[m] + hz[m] + b_z);
        float ng = tanh_(an[m] + bin + r * (hn[m] + bhn));
        float hj = sH[(r0 + m) * 32 + j];
        float o = fmaxf((1.f - z) * ng + z * hj, 0.f);
        out[(size_t)(nb + r0 + m) * H + j] = o;
        outh[(size_t)(nb + r0 + m) * H + j] = (half_t)o;
    }
}

// ---------- K6: GRU layer2 + log_softmax. aggX is [N,32] (W2p folded into Wc) ----------
__global__ __launch_bounds__(320) void k6_gru2(const float* __restrict__ aggX,  // [N,32]
                                               const float* __restrict__ h2,    // [N,40]
                                               const float* __restrict__ Wc,    // [32][120] k-major
                                               const float* __restrict__ WhT,   // [40][120] k-major
                                               const float* __restrict__ bih,
                                               const float* __restrict__ bhh,
                                               float* __restrict__ out) {
    // smem: sA[1024] | sH[1280] | sWc[3840] | sWT[4800] | sLs[32]; sOut(32x41=1312) overlays sA+sH head
    __shared__ float smem[10976];
    float* sA = smem;
    float* sH = smem + 1024;
    float* sWc = smem + 2304;
    float* sWT = smem + 6144;
    float* sLs = smem + 10944;
    int tid = threadIdx.x;
    int nb = blockIdx.x * 32;
    if (tid < 256) ((float4*)sA)[tid] = ((const float4*)(aggX + (size_t)nb * H))[tid];
    ((float4*)sH)[tid] = ((const float4*)(h2 + (size_t)nb * NC))[tid];
    for (int i = tid; i < 960; i += 320) ((float4*)sWc)[i] = ((const float4*)Wc)[i];
    for (int i = tid; i < 1200; i += 320) ((float4*)sWT)[i] = ((const float4*)WhT)[i];
    __syncthreads();
    int j = tid % NC, slot = tid / NC;
    int r0 = slot * 4;
    float ar[4] = {0, 0, 0, 0}, az[4] = {0, 0, 0, 0}, an[4] = {0, 0, 0, 0};
    float hr[4] = {0, 0, 0, 0}, hz[4] = {0, 0, 0, 0}, hn[4] = {0, 0, 0, 0};
#pragma unroll
    for (int kc = 0; kc < 8; ++kc) {  // input side: K=32
        float4 a4[4];
#pragma unroll
        for (int m = 0; m < 4; ++m) a4[m] = *(const float4*)&sA[(r0 + m) * 32 + kc * 4];
#pragma unroll
        for (int kk = 0; kk < 4; ++kk) {
            int k = kc * 4 + kk;
            float wr = sWc[k * 120 + j], wz = sWc[k * 120 + 40 + j], wn = sWc[k * 120 + 80 + j];
#pragma unroll
            for (int m = 0; m < 4; ++m) {
                float ak = ((const float*)&a4[m])[kk];
                ar[m] += wr * ak; az[m] += wz * ak; an[m] += wn * ak;
            }
        }
    }
#pragma unroll
    for (int kc = 0; kc < 10; ++kc) {  // hidden side: K=40
        float4 h4[4];
#pragma unroll
        for (int m = 0; m < 4; ++m) h4[m] = *(const float4*)&sH[(r0 + m) * 40 + kc * 4];
#pragma unroll
        for (int kk = 0; kk < 4; ++kk) {
            int k = kc * 4 + kk;
            float ur = sWT[k * 120 + j], uz = sWT[k * 120 + 40 + j], un = sWT[k * 120 + 80 + j];
#pragma unroll
            for (int m = 0; m < 4; ++m) {
                float hk = ((const float*)&h4[m])[kk];
                hr[m] += ur * hk; hz[m] += uz * hk; hn[m] += un * hk;
            }
        }
    }
    float b_r = bih[j] + bhh[j];
    float b_z = bih[NC + j] + bhh[NC + j];
    float bin = bih[2 * NC + j];
    float bhn = bhh[2 * NC + j];
    float v[4];
#pragma unroll
    for (int m = 0; m < 4; ++m) {
        float r = sigm_(ar[m] + hr[m] + b_r);
        float z = sigm_(az[m] + hz[m] + b_z);
        float ng = tanh_(an[m] + bin + r * (hn[m] + bhn));
        float hj = sH[(r0 + m) * 40 + j];
        v[m] = (1.f - z) * ng + z * hj;
    }
    __syncthreads();  // all reads of sA/sH done before overlay
    float* sOut = smem;  // 32x41, stride 41 -> conflict-free column reads
#pragma unroll
    for (int m = 0; m < 4; ++m) sOut[(r0 + m) * 41 + j] = v[m];
    __syncthreads();
    if (tid < 32) {
        const float* row = sOut + tid * 41;
        float mx = row[0];
#pragma unroll
        for (int t = 1; t < NC; ++t) mx = fmaxf(mx, row[t]);
        float s = 0.f;
#pragma unroll
        for (int t = 0; t < NC; ++t) s += __expf(row[t] - mx);
        sLs[tid] = mx + __logf(s);
    }
    __syncthreads();
#pragma unroll
    for (int m = 0; m < 4; ++m)
        out[(size_t)(nb + r0 + m) * NC + j] = v[m] - sLs[r0 + m];
}

extern "C" void kernel_launch(void* const* d_in, const int* in_sizes, int n_in,
                              void* d_out, int out_size, void* d_ws, size_t ws_size,
                              hipStream_t stream) {
    const float* x = (const float*)d_in[0];
    const int* ei = (const int*)d_in[1];
    const float* ew = (const float*)d_in[2];
    const float* W1p = (const float*)d_in[3];
    const float* W1m = (const float*)d_in[4];
    const float* g1wih = (const float*)d_in[5];
    const float* g1whh = (const float*)d_in[6];
    const float* g1bih = (const float*)d_in[7];
    const float* g1bhh = (const float*)d_in[8];
    const float* W2p = (const float*)d_in[9];
    const float* W2m = (const float*)d_in[10];
    const float* g2wih = (const float*)d_in[11];
    const float* g2whh = (const float*)d_in[12];
    const float* g2bih = (const float*)d_in[13];
    const float* g2bhh = (const float*)d_in[14];
    float* ws = (float*)d_ws;

    // workspace layout (float indices), ~57 MB total:
    float* A = ws + 0;                       // h1 [N,32] then h2 [N,40] (fp32)
    float* B = ws + 4000000;                 // agg [N,32] fp32, both layers
    half_t* Hh = (half_t*)(ws + 8000000);    // fp16 gather table [N,32]: h1h then hreluh
    int2* rec = (int2*)ws;                   // CSR-build scratch, overlays A+B (dead before k1)
    int2* evs = (int2*)(ws + 9600000);       // 196*CAP sorted records (17.7 MB)
    int* ofs = (int*)(ws + 14015488);        // 100000
    int* ocn = (int*)(ws + 14115488);        // 100000
    int* gcur = (int*)(ws + 14215488);       // 196
    float* Wc1 = ws + 14215684;              // 3072
    float* Wc2c = Wc1 + 3072;                // 3840
    float* WhT1 = Wc2c + 3840;               // 3072
    float* WhT2 = WhT1 + 3072;               // 4800
    float* hrelu = (float*)d_out;            // [N,32] fp32, overlays d_out; k6 overwrites later
    float* out = (float*)d_out;

    // ---- CSR build (shared by both layers) ----
    hipMemsetAsync(gcur, 0, NBK * sizeof(int), stream);
    kA_bucket<<<(NE + EPB - 1) / EPB, 256, 0, stream>>>(ei, ew, gcur, rec);
    kB_sort<<<NBK, 256, 0, stream>>>(gcur, rec, evs, ofs, ocn);
    k_wc<<<(3072 + 3840 + 3072 + 4800 + 255) / 256, 256, 0, stream>>>(
        W1m, g1wih, W2p, W2m, g2wih, g1whh, g2whh, Wc1, Wc2c, WhT1, WhT2);

    // ---- layer 1 ----
    k1_proj<<<(NN + 7) / 8, 256, 0, stream>>>(x, W1p, A, Hh);
    k_aggh<<<(NN * 4 + 255) / 256, 256, 0, stream>>>(ofs, ocn, evs, (const half8*)Hh, B);
    k3_gru1<<<NN / 32, 256, 0, stream>>>(B, A, Wc1, WhT1, g1bih, g1bhh, hrelu, Hh);

    // ---- layer 2 ----
    k4_proj2<<<(NN + 7) / 8, 320, 0, stream>>>(hrelu, W2p, A);
    k_aggh<<<(NN * 4 + 255) / 256, 256, 0, stream>>>(ofs, ocn, evs, (const half8*)Hh, B);
    k6_gru2<<<NN / 32, 320, 0, stream>>>(B, A, Wc2c, WhT2, g2bih, g2bhh, out);
}

// Round 8
// 361.362 us; speedup vs baseline: 21.8798x; 1.0740x over previous
//
#include <hip/hip_runtime.h>
#include <math.h>

#define NN 100000
#define NP 100032   // 64 * 1563 (padded node count)
#define NE 2000000
#define FIN 32
#define H 32
#define NC 40

#define NBK 196      // coarse buckets: dst>>9 (512 nodes each)
#define BSH 9
#define CAP 11264    // per-bucket capacity: mean 10240 + ~10 sigma
#define EPT 16
#define EPB (256 * EPT)  // 4096 edges per block

typedef _Float16 half_t;
typedef __attribute__((ext_vector_type(8))) _Float16 half8;
typedef __attribute__((ext_vector_type(4))) float f32x4;

__device__ __forceinline__ float sigm_(float x) {
    return 1.0f / (1.0f + __expf(-x));
}
__device__ __forceinline__ float tanh_(float x) {
    x = fminf(fmaxf(x, -20.0f), 20.0f);
    float e = __expf(2.0f * x);
    return (e - 1.0f) / (e + 1.0f);
}

// ---------- phase A: coarse-bucket scatter; per-edge atomics are LDS-only ----------
__global__ __launch_bounds__(256) void kA_bucket(const int* __restrict__ ei,
                                                 const float* __restrict__ ew,
                                                 int* __restrict__ gcur,
                                                 int2* __restrict__ rec) {
    __shared__ int cnt[NBK], base[NBK];
    int tid = threadIdx.x;
    for (int i = tid; i < NBK; i += 256) cnt[i] = 0;
    __syncthreads();
    int e0 = blockIdx.x * EPB;
    for (int i = 0; i < EPT; ++i) {
        int e = e0 + i * 256 + tid;
        if (e < NE) atomicAdd(&cnt[ei[NE + e] >> BSH], 1);
    }
    __syncthreads();
    for (int i = tid; i < NBK; i += 256) {
        base[i] = atomicAdd(&gcur[i], cnt[i]);  // one global atomic per (block,bucket)
        cnt[i] = 0;
    }
    __syncthreads();
    for (int i = 0; i < EPT; ++i) {
        int e = e0 + i * 256 + tid;
        if (e < NE) {
            int d = ei[NE + e], s = ei[e];
            int b = d >> BSH;
            int r = atomicAdd(&cnt[b], 1);
            int pos = base[b] + r;
            if (pos < CAP)  // statistically impossible overflow guard
                rec[(size_t)b * CAP + pos] =
                    make_int2(s | ((d & 511) << 17), __float_as_int(ew[e]));
        }
    }
}

// ---------- phase B: per-bucket local counting sort (LDS hist + scan + rank) ----------
__global__ __launch_bounds__(256) void kB_sort(const int* __restrict__ gcur,
                                               const int2* __restrict__ rec,
                                               int2* __restrict__ evs,
                                               int* __restrict__ ofs,
                                               int* __restrict__ ocn) {
    __shared__ int hist[512], lofs[512], ssc[256];
    int tid = threadIdx.x, b = blockIdx.x;
    int nb0 = b << BSH;
    int nnodes = min(512, NN - nb0);
    int cntb = min(gcur[b], CAP);
    hist[tid] = 0;
    hist[tid + 256] = 0;
    __syncthreads();
    const int2* rb = rec + (size_t)b * CAP;
    for (int i = tid; i < cntb; i += 256)
        atomicAdd(&hist[(rb[i].x >> 17) & 511], 1);
    __syncthreads();
    int ps = hist[2 * tid] + hist[2 * tid + 1];
    ssc[tid] = ps;
    __syncthreads();
    for (int off = 1; off < 256; off <<= 1) {
        int v = (tid >= off) ? ssc[tid - off] : 0;
        __syncthreads();
        ssc[tid] += v;
        __syncthreads();
    }
    int ex = ssc[tid] - ps;  // exclusive over pairs
    lofs[2 * tid] = ex;
    lofs[2 * tid + 1] = ex + hist[2 * tid];
    __syncthreads();
    for (int l = tid; l < nnodes; l += 256) {  // per-node CSR meta (coalesced)
        ofs[nb0 + l] = b * CAP + lofs[l];
        ocn[nb0 + l] = hist[l];
    }
    hist[tid] = 0;  // same thread zeroes exactly the bins it read above
    hist[tid + 256] = 0;
    __syncthreads();
    int2* eb = evs + (size_t)b * CAP;
    for (int i = tid; i < cntb; i += 256) {
        int2 r = rb[i];
        int dl = (r.x >> 17) & 511;
        int rk = atomicAdd(&hist[dl], 1);
        eb[lofs[dl] + rk] = make_int2(r.x & 0x1FFFF, r.y);
    }
}

// ---------- build MFMA B-fragment-linear fp16 weight tables ----------
// Layer1: cols 0..31 r(fused K=64), 32..63 z(fused), 64..95 i_n(k<32), 96..127 h_n(k>=32)
//   W1sw[(s*8+ct)*64 + lane][0..7]: k = s*32+(lane>>4)*8+j, col = ct*16+(lane&15)
// Layer2: gate blocks of 48 cols (40 used): r 0..47, z 48..95, i_n 96..143, h_n 144..191
//   K padded to 96 (k<32 input=W2p@W2m@wih2^T fold, 32<=k<72 hidden=whh2^T, else 0)
__global__ __launch_bounds__(256) void k_wc(const float* __restrict__ W1m,
                                            const float* __restrict__ wih1,
                                            const float* __restrict__ W2p,
                                            const float* __restrict__ W2m,
                                            const float* __restrict__ wih2,
                                            const float* __restrict__ whh1,
                                            const float* __restrict__ whh2,
                                            half_t* __restrict__ W1sw,
                                            half_t* __restrict__ W2sw) {
    int i = blockIdx.x * 256 + threadIdx.x;
    if (i < 8192) {
        int j = i & 7, lane = (i >> 3) & 63, ct = (i >> 9) & 7, s = i >> 12;
        int k = s * 32 + (lane >> 4) * 8 + j;
        int col = ct * 16 + (lane & 15);
        int g = col >> 5, jj = col & 31;
        float v = 0.f;
        if (g <= 2) {
            if (k < 32) {  // input side (agg): fold W1m @ wih1^T
                float acc = 0.f;
                for (int t = 0; t < H; ++t) acc += W1m[k * H + t] * wih1[(g * H + jj) * H + t];
                v = acc;
            } else if (g < 2) {  // r,z hidden side
                v = whh1[(g * H + jj) * H + (k - 32)];
            }                     // g==2 (i_n), k>=32 -> 0
        } else {                  // g==3 (h_n): hidden side only
            if (k >= 32) v = whh1[(2 * H + jj) * H + (k - 32)];
        }
        W1sw[i] = (half_t)v;
    } else if (i < 8192 + 18432) {
        int i2 = i - 8192;
        int j = i2 & 7, lane = (i2 >> 3) & 63;
        int tt = i2 >> 9;  // 0..35
        int ct = tt % 12, s = tt / 12;
        int k = s * 32 + (lane >> 4) * 8 + j;  // 0..95
        int col = ct * 16 + (lane & 15);       // 0..191
        int g = col / 48, jj = col % 48;
        float v = 0.f;
        if (jj < NC) {
            if (g <= 2) {
                if (k < 32) {  // input side (aggX): fold W2p @ W2m @ wih2^T
                    float acc = 0.f;
                    for (int u = 0; u < NC; ++u) {
                        float s2 = 0.f;
                        for (int t = 0; t < NC; ++t)
                            s2 += W2m[u * NC + t] * wih2[(g * NC + jj) * NC + t];
                        acc += W2p[k * NC + u] * s2;
                    }
                    v = acc;
                } else if (k < 72 && g < 2) {  // r,z hidden side
                    v = whh2[(g * NC + jj) * NC + (k - 32)];
                }
            } else {  // g==3 (h_n)
                if (k >= 32 && k < 72) v = whh2[(2 * NC + jj) * NC + (k - 32)];
            }
        }
        W2sw[i2] = (half_t)v;
    }
}

// ---------- K1: h1 = x @ W1p -> fp16 into Xc1 cols 32..63 (stride 64) ----------
__global__ __launch_bounds__(256) void k1_proj(const float* __restrict__ x,
                                               const float* __restrict__ Wp,
                                               half_t* __restrict__ Xc1) {
    __shared__ float sWp[FIN * H];
    __shared__ float sx[8][FIN];
    int tid = threadIdx.x;
    for (int i = tid; i < FIN * H; i += 256) sWp[i] = Wp[i];
    int nb = blockIdx.x * 8;
    int nl = tid >> 5, j = tid & 31;
    int n = nb + nl;
    if (n < NN) sx[nl][j] = x[(size_t)n * FIN + j];
    __syncthreads();
    float acc = 0.f;
#pragma unroll
    for (int k = 0; k < FIN; ++k) acc += sx[nl][k] * sWp[k * H + j];
    if (n < NN) Xc1[(size_t)n * 64 + 32 + j] = (half_t)acc;
}

// ---------- K4: h2 = hrelu @ W2p -> fp16 into Xc2 cols 32..71 (stride 96); zero pad 72..95 ----------
__global__ __launch_bounds__(320) void k4_proj2(const half_t* __restrict__ Hh,
                                                const float* __restrict__ Wp,
                                                half_t* __restrict__ Xc2) {
    __shared__ float sWp[FIN * NC];
    __shared__ float shn[8][FIN];
    int tid = threadIdx.x;
    for (int i = tid; i < FIN * NC; i += 320) sWp[i] = Wp[i];
    int nb = blockIdx.x * 8;
    if (tid < 256) {
        int r = tid >> 5, c = tid & 31;
        shn[r][c] = (float)Hh[(size_t)(nb + r) * 32 + c];
    }
    // zero K-pad cols 72..95: this region overlays stale CSR-build scratch whose
    // bit patterns can be fp16-NaN, and MFMA 0*NaN = NaN (round-7 failure).
    if (tid < 192) {
        int r = tid / 24, c = tid % 24;
        Xc2[(size_t)(nb + r) * 96 + 72 + c] = (half_t)0.f;
    }
    __syncthreads();
    int nl = tid / NC, j = tid % NC;
    int n = nb + nl;
    float acc = 0.f;
#pragma unroll
    for (int k = 0; k < FIN; ++k) acc += shn[nl][k] * sWp[k * NC + j];
    if (n < NN) Xc2[(size_t)n * 96 + 32 + j] = (half_t)acc;
}

// ---------- aggregation: fp16 gather, fp32 accum, fp16 strided store ----------
// 4 threads/node; src row = src + n*(sstr8*8) halves; dst row = dst + n*dstr halves.
__global__ __launch_bounds__(256) void k_aggh(const int* __restrict__ ofs,
                                              const int* __restrict__ ocn,
                                              const int2* __restrict__ evs,
                                              const half_t* __restrict__ src, int sstr8,
                                              half_t* __restrict__ dst, int dstr) {
    int idx = blockIdx.x * 256 + threadIdx.x;
    int n = idx >> 2, q = idx & 3;
    if (n >= NN) return;
    const half8* s8 = (const half8*)src;
    int s0 = ofs[n], c = ocn[n];
    float acc[8] = {0.f, 0.f, 0.f, 0.f, 0.f, 0.f, 0.f, 0.f};
    for (int e = s0; e < s0 + c; ++e) {
        int2 r = evs[e];
        float w = __int_as_float(r.y);
        half8 hv = s8[(size_t)r.x * sstr8 + q];
#pragma unroll
        for (int t = 0; t < 8; ++t) acc[t] += w * (float)hv[t];
    }
    half8 o;
#pragma unroll
    for (int t = 0; t < 8; ++t) o[t] = (half_t)acc[t];
    *(half8*)(dst + (size_t)n * dstr + q * 8) = o;
}

// ---------- K3: GRU layer1 + relu via MFMA. 4 waves x 16 nodes, no LDS ----------
__global__ __launch_bounds__(256) void k3m(const half_t* __restrict__ Xc1,
                                           const half8* __restrict__ W1sw,
                                           const float* __restrict__ bih,
                                           const float* __restrict__ bhh,
                                           half_t* __restrict__ Hh) {
    int tid = threadIdx.x;
    int wave = tid >> 6, lane = tid & 63;
    int m16 = lane & 15, q = lane >> 4;
    int nb = blockIdx.x * 64 + wave * 16;
    const half8* xr = (const half8*)(Xc1 + (size_t)(nb + m16) * 64);
    half8 a0 = xr[q];      // k = q*8..q*8+7
    half8 a1 = xr[4 + q];  // k = 32+q*8..
    f32x4 acc[8];
#pragma unroll
    for (int ct = 0; ct < 8; ++ct) acc[ct] = (f32x4){0.f, 0.f, 0.f, 0.f};
#pragma unroll
    for (int ct = 0; ct < 8; ++ct) {
        acc[ct] = __builtin_amdgcn_mfma_f32_16x16x32_f16(a0, W1sw[ct * 64 + lane], acc[ct], 0, 0, 0);
        acc[ct] = __builtin_amdgcn_mfma_f32_16x16x32_f16(a1, W1sw[(8 + ct) * 64 + lane], acc[ct], 0, 0, 0);
    }
#pragma unroll
    for (int ct = 0; ct < 2; ++ct) {
        int j = ct * 16 + m16;
        float br = bih[j] + bhh[j];
        float bz = bih[H + j] + bhh[H + j];
        float bi = bih[2 * H + j], bh = bhh[2 * H + j];
#pragma unroll
        for (int m = 0; m < 4; ++m) {
            int node = nb + q * 4 + m;  // C/D: row = quad*4 + reg, col = lane&15
            float r = sigm_(acc[ct][m] + br);
            float z = sigm_(acc[2 + ct][m] + bz);
            float ng = tanh_(acc[4 + ct][m] + bi + r * (acc[6 + ct][m] + bh));
            float hj = (float)Xc1[(size_t)node * 64 + 32 + j];
            float o = fmaxf((1.f - z) * ng + z * hj, 0.f);
            if (node < NN) Hh[(size_t)node * 32 + j] = (half_t)o;
        }
    }
}

// ---------- K6: GRU layer2 + log_softmax via MFMA + shfl reduce, no LDS ----------
__global__ __launch_bounds__(256) void k6m(const half_t* __restrict__ Xc2,
                                           const half8* __restrict__ W2sw,
                                           const float* __restrict__ bih,
                                           const float* __restrict__ bhh,
                                           float* __restrict__ out) {
    int tid = threadIdx.x;
    int wave = tid >> 6, lane = tid & 63;
    int m16 = lane & 15, q = lane >> 4;
    int nb = blockIdx.x * 64 + wave * 16;
    const half8* xr = (const half8*)(Xc2 + (size_t)(nb + m16) * 96);
    half8 a0 = xr[q], a1 = xr[4 + q], a2 = xr[8 + q];
    f32x4 acc[12];
#pragma unroll
    for (int ct = 0; ct < 12; ++ct) acc[ct] = (f32x4){0.f, 0.f, 0.f, 0.f};
#pragma unroll
    for (int ct = 0; ct < 12; ++ct) {
        acc[ct] = __builtin_amdgcn_mfma_f32_16x16x32_f16(a0, W2sw[ct * 64 + lane], acc[ct], 0, 0, 0);
        acc[ct] = __builtin_amdgcn_mfma_f32_16x16x32_f16(a1, W2sw[(12 + ct) * 64 + lane], acc[ct], 0, 0, 0);
        acc[ct] = __builtin_amdgcn_mfma_f32_16x16x32_f16(a2, W2sw[(24 + ct) * 64 + lane], acc[ct], 0, 0, 0);
    }
    float v[3][4];
#pragma unroll
    for (int ct = 0; ct < 3; ++ct) {
        int j = ct * 16 + m16;
        int jc = (j < NC) ? j : (NC - 1);  // clamp (lanes with j>=40 produce unused values)
        float br = bih[jc] + bhh[jc];
        float bz = bih[NC + jc] + bhh[NC + jc];
        float bi = bih[2 * NC + jc], bh = bhh[2 * NC + jc];
#pragma unroll
        for (int m = 0; m < 4; ++m) {
            int node = nb + q * 4 + m;
            float r = sigm_(acc[ct][m] + br);
            float z = sigm_(acc[3 + ct][m] + bz);
            float ng = tanh_(acc[6 + ct][m] + bi + r * (acc[9 + ct][m] + bh));
            float hj = (float)Xc2[(size_t)node * 96 + 32 + jc];
            v[ct][m] = (1.f - z) * ng + z * hj;
        }
    }
    bool v2ok = (m16 < 8);  // ct=2 covers j=32..39 only for m16<8
#pragma unroll
    for (int m = 0; m < 4; ++m) {
        float mx = fmaxf(v[0][m], v[1][m]);
        if (v2ok) mx = fmaxf(mx, v[2][m]);
#pragma unroll
        for (int d = 1; d < 16; d <<= 1) mx = fmaxf(mx, __shfl_xor(mx, d));
        float se = __expf(v[0][m] - mx) + __expf(v[1][m] - mx) +
                   (v2ok ? __expf(v[2][m] - mx) : 0.f);
#pragma unroll
        for (int d = 1; d < 16; d <<= 1) se += __shfl_xor(se, d);
        float ls = mx + __logf(se);
        int node = nb + q * 4 + m;
        if (node < NN) {
            out[(size_t)node * NC + m16] = v[0][m] - ls;
            out[(size_t)node * NC + 16 + m16] = v[1][m] - ls;
            if (v2ok) out[(size_t)node * NC + 32 + m16] = v[2][m] - ls;
        }
    }
}

extern "C" void kernel_launch(void* const* d_in, const int* in_sizes, int n_in,
                              void* d_out, int out_size, void* d_ws, size_t ws_size,
                              hipStream_t stream) {
    const float* x = (const float*)d_in[0];
    const int* ei = (const int*)d_in[1];
    const float* ew = (const float*)d_in[2];
    const float* W1p = (const float*)d_in[3];
    const float* W1m = (const float*)d_in[4];
    const float* g1wih = (const float*)d_in[5];
    const float* g1whh = (const float*)d_in[6];
    const float* g1bih = (const float*)d_in[7];
    const float* g1bhh = (const float*)d_in[8];
    const float* W2p = (const float*)d_in[9];
    const float* W2m = (const float*)d_in[10];
    const float* g2wih = (const float*)d_in[11];
    const float* g2whh = (const float*)d_in[12];
    const float* g2bih = (const float*)d_in[13];
    const float* g2bhh = (const float*)d_in[14];
    float* ws = (float*)d_ws;

    // workspace layout (float indices), ~44 MB total:
    half_t* Xc = (half_t*)ws;                 // [NP][64] layer1 / [NP][96] layer2 fp16 activations (4,801,536 f)
    half_t* Hh = (half_t*)(ws + 4801536);     // [NP][32] fp16 hrelu gather table (1,600,512 f)
    int2* rec = (int2*)ws;                    // CSR-build scratch (4,415,488 f) — dead before k1, overlays Xc
    int2* evs = (int2*)(ws + 6402048);        // 196*CAP sorted records (4,415,488 f)
    int* ofs = (int*)(ws + 10817536);         // 100,000
    int* ocn = (int*)(ws + 10917536);         // 100,000
    int* gcur = (int*)(ws + 11017536);        // 196 (+pad)
    half_t* W1sw = (half_t*)(ws + 11017792);  // 8,192 halves (4,096 f)
    half_t* W2sw = W1sw + 8192;               // 18,432 halves (9,216 f)
    float* out = (float*)d_out;

    // ---- CSR build (shared by both layers) ----
    hipMemsetAsync(gcur, 0, NBK * sizeof(int), stream);
    kA_bucket<<<(NE + EPB - 1) / EPB, 256, 0, stream>>>(ei, ew, gcur, rec);
    kB_sort<<<NBK, 256, 0, stream>>>(gcur, rec, evs, ofs, ocn);
    k_wc<<<(8192 + 18432 + 255) / 256, 256, 0, stream>>>(
        W1m, g1wih, W2p, W2m, g2wih, g1whh, g2whh, W1sw, W2sw);

    // ---- layer 1 ----
    k1_proj<<<NN / 8, 256, 0, stream>>>(x, W1p, Xc);
    k_aggh<<<(NN * 4 + 255) / 256, 256, 0, stream>>>(ofs, ocn, evs, Xc + 32, 8, Xc, 64);
    k3m<<<NP / 64, 256, 0, stream>>>(Xc, (const half8*)W1sw, g1bih, g1bhh, Hh);

    // ---- layer 2 ----
    k4_proj2<<<NN / 8, 320, 0, stream>>>(Hh, W2p, Xc);
    k_aggh<<<(NN * 4 + 255) / 256, 256, 0, stream>>>(ofs, ocn, evs, Hh, 4, Xc, 96);
    k6m<<<NP / 64, 256, 0, stream>>>(Xc, (const half8*)W2sw, g2bih, g2bhh, out);
}